// Round 4
// baseline (403.646 us; speedup 1.0000x reference)
//
#include <hip/hip_runtime.h>

// ---------------------------------------------------------------------------
// CausalAttention: B=8, S=2048, D=1024, fp32 in, fp32 out.
// Round 9: r8 structure + REGISTER-LEVEL FRAGMENT PREFETCH.
//   r8 post-mortem: MfmaUtil 38% because phase time = LDS-read time (~500cy)
//   + MFMA time (~310cy) SERIALIZED (lockstep: reads and their consuming
//   MFMAs in the same phase). Fix: read tile t+1's fragments into a second
//   named register set DURING tile t's MFMA cluster; wait at next phase top.
//   - BM=BN=256, BK=32, 8 waves (2Mx4N), 512 thr, LDS 128KB = 4 slots
//   - unit row-major [256][32]h; chunk u -> (row=u>>2, col=u&3): coalesced
//   - both-sides XOR swizzle (r8-validated): store chunk (row,c) at
//     (row, c ^ ((row>>1)&3)) via pre-swizzled GLOBAL source, same XOR on
//     frag read. XOR term is i-independent (row+=16 preserves (row>>1)&3)
//     -> frag addrs = 1 base + imm offsets i*1024B.
//   - phase t: [lgkm(0) | vmcnt(8) | barrier | STAGE t+4 | ds_read t+1 regs
//     || 32 MFMA on t's regs].  lgkm(0)-before-barrier = WAR fence for the
//     slot t&3 overwrite AND the RAW fence for this phase's MFMA operands.
//     vmcnt tail 8/4/0; never 0 mid-loop.
//   ws: Q 32 | K 32 | Vt 32 | Sc 64  (xh@Sc+0 32MB, Wh@Sc+32MB 6MB)
// ---------------------------------------------------------------------------

typedef _Float16 v8h __attribute__((ext_vector_type(8)));
typedef _Float16 v4h __attribute__((ext_vector_type(4)));
typedef float    v4f __attribute__((ext_vector_type(4)));

#define BM 256
#define BN 256

__device__ __forceinline__ void async16(const _Float16* g, _Float16* l) {
  // global -> LDS direct copy, 16B/lane; LDS dest = wave-uniform base,
  // HW adds lane*16.  [validated r4]
  __builtin_amdgcn_global_load_lds(
      (__attribute__((address_space(1))) void*)(void*)g,
      (__attribute__((address_space(3))) void*)l, 16, 0, 0);
}

// 12 ds_read_b128: one base addr per operand + immediate offsets.
__device__ __forceinline__ void read_frags(const _Float16* lds, int slot,
                                           int offA0, int offB0,
                                           v8h a[8], v8h b[4]) {
  const _Float16* base = lds + slot * 16384;
#pragma unroll
  for (int i = 0; i < 8; ++i) a[i] = *(const v8h*)(base + offA0 + i * 512);
#pragma unroll
  for (int j = 0; j < 4; ++j) b[j] = *(const v8h*)(base + offB0 + j * 512);
}

__device__ __forceinline__ void mfma_cluster(const v8h a[8], const v8h b[4],
                                             v4f acc[8][4]) {
  __builtin_amdgcn_s_setprio(1);
#pragma unroll
  for (int i = 0; i < 8; ++i)
#pragma unroll
    for (int j = 0; j < 4; ++j)
      acc[i][j] = __builtin_amdgcn_mfma_f32_16x16x32_f16(a[i], b[j],
                                                         acc[i][j], 0, 0, 0);
  __builtin_amdgcn_s_setprio(0);
}

// ---------------------------------------------------------------------------
// Shared deep-pipelined GEMM loop with register fragment prefetch.
// NKT = number of 32-wide k-tiles (>=4, even).  acc[8][4] per wave;
// wave grid 2Mx4N (wr in {0,128}, wc in {0,64,128,192}).
// ---------------------------------------------------------------------------
__device__ __forceinline__ void gemm_loop(const _Float16* Ab, int lda,
                                          const _Float16* Bb, int ldb,
                                          int NKT, _Float16* lds,
                                          int w, int lane, int wr, int wc,
                                          int lr, int quad, v4f acc[8][4]) {
  // fragment base offsets (elements); XOR term invariant across i (see hdr)
  const int offA0 = (wr + lr) * 32 + ((quad ^ (((wr + lr) >> 1) & 3)) * 8);
  const int offB0 = 8192 + (wc + lr) * 32 + ((quad ^ (((wc + lr) >> 1) & 3)) * 8);

  // staging: chunk u = w*128 + g*64 + lane; row=u>>2, c=u&3; pre-swizzled
  // global source col = c ^ ((row>>1)&3)  (involution).
  const int u0 = w * 128 + lane;
  const int u1 = u0 + 64;
  const int r0 = u0 >> 2, c0 = (u0 & 3) ^ ((r0 >> 1) & 3);
  const int r1 = u1 >> 2, c1 = (u1 & 3) ^ ((r1 >> 1) & 3);
  const _Float16* pA0 = Ab + (size_t)r0 * lda + c0 * 8;
  const _Float16* pA1 = Ab + (size_t)r1 * lda + c1 * 8;
  const _Float16* pB0 = Bb + (size_t)r0 * ldb + c0 * 8;
  const _Float16* pB1 = Bb + (size_t)r1 * ldb + c1 * 8;
  const int dA0 = (w * 128) * 8;        // wave-uniform chunk base * 8 elems
  const int dA1 = (w * 128 + 64) * 8;

#define STAGE(T)                                                             \
  do {                                                                       \
    _Float16* Ld = lds + ((T) & 3) * 16384;                                  \
    async16(pA0 + (T) * 32, Ld + dA0);                                       \
    async16(pB0 + (T) * 32, Ld + 8192 + dA0);                                \
    async16(pA1 + (T) * 32, Ld + dA1);                                       \
    async16(pB1 + (T) * 32, Ld + 8192 + dA1);                                \
  } while (0)

  // lgkm(0): my frag reads of tile T landed (MFMA RAW + slot-T&3 WAR fence);
  // vmcnt(N)+barrier: tile T+1 resident on ALL waves.
#define SYNC(T)                                                              \
  do {                                                                       \
    asm volatile("s_waitcnt lgkmcnt(0)" ::: "memory");                       \
    __builtin_amdgcn_sched_barrier(0);                                       \
    if ((T) <= NKT - 4)                                                      \
      asm volatile("s_waitcnt vmcnt(8)" ::: "memory");                       \
    else if ((T) == NKT - 3)                                                 \
      asm volatile("s_waitcnt vmcnt(4)" ::: "memory");                       \
    else                                                                     \
      asm volatile("s_waitcnt vmcnt(0)" ::: "memory");                       \
    __builtin_amdgcn_s_barrier();                                            \
  } while (0)

  v8h a0[8], b0[4], a1[8], b1[4];

  // prologue: fill all 4 slots (16 glds); confirm tile 0; read its frags.
  STAGE(0);
  STAGE(1);
  STAGE(2);
  STAGE(3);
  asm volatile("s_waitcnt vmcnt(12)" ::: "memory");
  __builtin_amdgcn_s_barrier();
  read_frags(lds, 0, offA0, offB0, a0, b0);

  for (int t = 0; t < NKT; t += 2) {
    // even half: consume (a0,b0)=tile t, prefetch tile t+1 into (a1,b1)
    SYNC(t);
    if (t + 4 < NKT) STAGE(t + 4);
    read_frags(lds, (t + 1) & 3, offA0, offB0, a1, b1);
    mfma_cluster(a0, b0, acc);

    // odd half: consume (a1,b1)=tile t+1, prefetch tile t+2 into (a0,b0)
    SYNC(t + 1);
    if (t + 5 < NKT) STAGE(t + 5);
    if (t + 2 < NKT) read_frags(lds, (t + 2) & 3, offA0, offB0, a0, b0);
    mfma_cluster(a1, b1, acc);
  }
#undef STAGE
#undef SYNC
}

// Bijective XCD-aware swizzle of the per-z 2D grid (requires nwg%8==0:
// proj 768, scores 64, pv 32 — all divisible).
__device__ __forceinline__ void grid_swz(int& bx, int& by) {
  const int gx = gridDim.x;
  const int n = gx * gridDim.y;
  const int f = blockIdx.x + blockIdx.y * gx;
  const int s = (f & 7) * (n >> 3) + (f >> 3);
  bx = s % gx;
  by = s / gx;
}

// ---------------------------------------------------------------------------
// fp32 -> fp16, 8 elems/thread.
// ---------------------------------------------------------------------------
__global__ __launch_bounds__(256)
void cvt_f16(const float* __restrict__ src, _Float16* __restrict__ dst) {
  const int i = (blockIdx.x * 256 + threadIdx.x) * 8;
  float4 a = *(const float4*)(src + i);
  float4 b = *(const float4*)(src + i + 4);
  v8h o = {(_Float16)a.x, (_Float16)a.y, (_Float16)a.z, (_Float16)a.w,
           (_Float16)b.x, (_Float16)b.y, (_Float16)b.z, (_Float16)b.w};
  *(v8h*)(dst + i) = o;
}

// ---------------------------------------------------------------------------
// Projection: C[m][n] = X[m][:] . W[n][:], n in [0,3072) packed Q|K|V.
// Q,K stored [16384][1024]; V transposed Vt[b][d][s].
// ---------------------------------------------------------------------------
__global__ __launch_bounds__(512, 2)
void proj_gemm(const _Float16* __restrict__ X, const _Float16* __restrict__ W,
               _Float16* __restrict__ Qb, _Float16* __restrict__ Kb,
               _Float16* __restrict__ Vt) {
  __shared__ _Float16 lds[65536];
  const int tid = threadIdx.x;
  int bx, by;
  grid_swz(bx, by);
  const int n0 = bx * BN, m0 = by * BM;
  const int which = n0 >> 10;                    // 0=Q 1=K 2=V, block-uniform
  const int nw = n0 & 1023;

  const int lane = tid & 63, w = tid >> 6;
  const int wr = (w >> 2) * 128, wc = (w & 3) * 64;
  const int lr = lane & 15, quad = lane >> 4;

  v4f acc[8][4];
#pragma unroll
  for (int i = 0; i < 8; ++i)
#pragma unroll
    for (int j = 0; j < 4; ++j) acc[i][j] = (v4f){0.f, 0.f, 0.f, 0.f};

  gemm_loop(X + (size_t)m0 * 1024, 1024, W + (size_t)n0 * 1024, 1024,
            32, lds, w, lane, wr, wc, lr, quad, acc);

  // C/D layout: col = lane&15, row = quad*4 + reg  [validated r4]
#pragma unroll
  for (int i = 0; i < 8; ++i) {
    const int r0 = m0 + wr + i * 16 + quad * 4;
#pragma unroll
    for (int j = 0; j < 4; ++j) {
      const int cl = wc + j * 16 + lr;
      if (which < 2) {
        _Float16* dst = (which == 0) ? Qb : Kb;
        const int col = nw + cl;
#pragma unroll
        for (int rg = 0; rg < 4; ++rg)
          dst[(size_t)(r0 + rg) * 1024 + col] = (_Float16)acc[i][j][rg];
      } else {
        const int d = nw + cl;
        const int b = r0 >> 11, s = r0 & 2047;   // 4 rows stay in-batch
        v4h o = {(_Float16)acc[i][j][0], (_Float16)acc[i][j][1],
                 (_Float16)acc[i][j][2], (_Float16)acc[i][j][3]};
        *(v4h*)(Vt + (size_t)b * 1024 * 2048 + (size_t)d * 2048 + s) = o;
      }
    }
  }
}

// ---------------------------------------------------------------------------
// Scores: Sc[b][q][k] = Q[b][q][:].K[b][k][:] (f16 raw), -inf where k > q.
// ---------------------------------------------------------------------------
__global__ __launch_bounds__(512, 2)
void scores_gemm(const _Float16* __restrict__ Q, const _Float16* __restrict__ K,
                 _Float16* __restrict__ Sc) {
  __shared__ _Float16 lds[65536];
  const int tid = threadIdx.x;
  int bx, by;
  grid_swz(bx, by);
  const int bz = blockIdx.z;
  const int n0 = bx * BN, m0 = by * BM;
  _Float16* Cb = Sc + (size_t)bz * 2048 * 2048;

  if (bx > by) {                                 // fully masked tile
    const _Float16 ninf = (_Float16)(-__builtin_inff());
    v8h mv = {ninf, ninf, ninf, ninf, ninf, ninf, ninf, ninf};
#pragma unroll
    for (int it = 0; it < 16; ++it) {
      int ch = it * 512 + tid;                   // v8h chunk in 256x256 tile
      int r = ch >> 5, cc = (ch & 31) * 8;
      *(v8h*)(Cb + (size_t)(m0 + r) * 2048 + n0 + cc) = mv;
    }
    return;
  }

  const _Float16* Qz = Q + (size_t)bz * 2048 * 1024;
  const _Float16* Kz = K + (size_t)bz * 2048 * 1024;

  const int lane = tid & 63, w = tid >> 6;
  const int wr = (w >> 2) * 128, wc = (w & 3) * 64;
  const int lr = lane & 15, quad = lane >> 4;

  v4f acc[8][4];
#pragma unroll
  for (int i = 0; i < 8; ++i)
#pragma unroll
    for (int j = 0; j < 4; ++j) acc[i][j] = (v4f){0.f, 0.f, 0.f, 0.f};

  gemm_loop(Qz + (size_t)m0 * 1024, 1024, Kz + (size_t)n0 * 1024, 1024,
            32, lds, w, lane, wr, wc, lr, quad, acc);

  const _Float16 ninf = (_Float16)(-__builtin_inff());
#pragma unroll
  for (int i = 0; i < 8; ++i) {
    const int r0 = m0 + wr + i * 16 + quad * 4;
#pragma unroll
    for (int j = 0; j < 4; ++j) {
      const int cc = n0 + wc + j * 16 + lr;
#pragma unroll
      for (int rg = 0; rg < 4; ++rg) {
        const int rr = r0 + rg;
        Cb[(size_t)rr * 2048 + cc] = (cc > rr) ? ninf : (_Float16)acc[i][j][rg];
      }
    }
  }
}

// ---------------------------------------------------------------------------
// Row softmax in place (f16), scale 1/32 inside exp.
// ---------------------------------------------------------------------------
__global__ __launch_bounds__(256)
void softmax_rows(_Float16* __restrict__ Sc) {
  _Float16* base = Sc + (size_t)blockIdx.x * 2048;
  const int tid = threadIdx.x;
  const int lane = tid & 63, w = tid >> 6;

  v8h pv = *(const v8h*)(base + tid * 8);
  float f[8];
#pragma unroll
  for (int j = 0; j < 8; ++j) f[j] = (float)pv[j];

  float mx = f[0];
#pragma unroll
  for (int j = 1; j < 8; ++j) mx = fmaxf(mx, f[j]);
#pragma unroll
  for (int off = 32; off; off >>= 1) mx = fmaxf(mx, __shfl_xor(mx, off));
  __shared__ float redm[4], reds[4];
  if (lane == 0) redm[w] = mx;
  __syncthreads();
  mx = fmaxf(fmaxf(redm[0], redm[1]), fmaxf(redm[2], redm[3]));

  const float scale = 0.03125f;                  // 1/sqrt(1024)
  float e[8], s = 0.f;
#pragma unroll
  for (int j = 0; j < 8; ++j) {
    e[j] = __expf((f[j] - mx) * scale);
    s += e[j];
  }
#pragma unroll
  for (int off = 32; off; off >>= 1) s += __shfl_xor(s, off);
  if (lane == 0) reds[w] = s;
  __syncthreads();
  s = reds[0] + reds[1] + reds[2] + reds[3];
  const float inv = 1.0f / s;
#pragma unroll
  for (int j = 0; j < 8; ++j) pv[j] = (_Float16)(e[j] * inv);
  *(v8h*)(base + tid * 8) = pv;
}

// ---------------------------------------------------------------------------
// Out (fp32): out[b][q][d] = sum_k P[b][q][k] * Vt[b][d][k]; K-loop causally
// truncated to (by+1)*256  -> NKT = (by+1)*8 >= 8 (even).
// ---------------------------------------------------------------------------
__global__ __launch_bounds__(512, 2)
void pv_gemm(const _Float16* __restrict__ P, const _Float16* __restrict__ Vt,
             float* __restrict__ Out) {
  __shared__ _Float16 lds[65536];
  const int tid = threadIdx.x;
  int bx, by;
  grid_swz(bx, by);
  const int bz = blockIdx.z;
  const int n0 = bx * BN, m0 = by * BM;
  const _Float16* Pb = P + (size_t)bz * 2048 * 2048;
  const _Float16* Vb = Vt + (size_t)bz * 1024 * 2048;
  float* Cb = Out + (size_t)bz * 2048 * 1024;

  const int lane = tid & 63, w = tid >> 6;
  const int wr = (w >> 2) * 128, wc = (w & 3) * 64;
  const int lr = lane & 15, quad = lane >> 4;

  v4f acc[8][4];
#pragma unroll
  for (int i = 0; i < 8; ++i)
#pragma unroll
    for (int j = 0; j < 4; ++j) acc[i][j] = (v4f){0.f, 0.f, 0.f, 0.f};

  gemm_loop(Pb + (size_t)m0 * 2048, 2048, Vb + (size_t)n0 * 2048, 2048,
            (by + 1) * 8, lds, w, lane, wr, wc, lr, quad, acc);

#pragma unroll
  for (int i = 0; i < 8; ++i) {
    const int r0 = m0 + wr + i * 16 + quad * 4;
#pragma unroll
    for (int j = 0; j < 4; ++j) {
      const int cc = n0 + wc + j * 16 + lr;
#pragma unroll
      for (int rg = 0; rg < 4; ++rg)
        Cb[(size_t)(r0 + rg) * 1024 + cc] = acc[i][j][rg];   // fp32 store
    }
  }
}

// ---------------------------------------------------------------------------
extern "C" void kernel_launch(void* const* d_in, const int* in_sizes, int n_in,
                              void* d_out, int out_size, void* d_ws, size_t ws_size,
                              hipStream_t stream) {
  const int B = 8, S = 2048, D = 1024;
  const int M = B * S;                           // 16384
  const float* x  = (const float*)d_in[0];
  const float* Wq = (const float*)d_in[1];
  const float* Wk = (const float*)d_in[2];
  const float* Wv = (const float*)d_in[3];
  float* out = (float*)d_out;

  // ws: Q 32MB | K 32MB | Vt 32MB | Sc 64MB (160 MB total, validated r4).
  // xh (32MB) and Wh (6MB) alias the head of Sc — dead before scores writes.
  char* ws = (char*)d_ws;
  _Float16* Qb = (_Float16*)ws;                          // [M][1024]
  _Float16* Kb = (_Float16*)(ws + (size_t)33554432);     // [M][1024]
  _Float16* Vt = (_Float16*)(ws + (size_t)67108864);     // [B][1024][2048]
  _Float16* Sc = (_Float16*)(ws + (size_t)100663296);    // [B][2048][2048]
  _Float16* xh = Sc;                                     // [M][1024]   (alias)
  _Float16* Wh = Sc + (size_t)M * D;                     // [3072][1024](alias)

  // 1) fp32 -> fp16 converts (memory-bound)
  cvt_f16<<<(M * D) / 2048, 256, 0, stream>>>(x, xh);
  cvt_f16<<<(D * D) / 2048, 256, 0, stream>>>(Wq, Wh);
  cvt_f16<<<(D * D) / 2048, 256, 0, stream>>>(Wk, Wh + (size_t)D * D);
  cvt_f16<<<(D * D) / 2048, 256, 0, stream>>>(Wv, Wh + (size_t)2 * D * D);

  // 2) QKV projection (256^2 pipelined GEMM, reg frag prefetch)
  proj_gemm<<<dim3(12, M / BM, 1), 512, 0, stream>>>(xh, Wh, Qb, Kb, Vt);

  // 3) raw scores with causal -inf mask
  scores_gemm<<<dim3(S / BN, S / BM, B), 512, 0, stream>>>(Qb, Kb, Sc);

  // 4) softmax rows in place
  softmax_rows<<<B * S, 256, 0, stream>>>(Sc);

  // 5) out = P @ Vt, fp32 store
  pv_gemm<<<dim3(D / BN, S / BM, B), 512, 0, stream>>>(Sc, Vt, out);
}

// Round 5
// 397.115 us; speedup vs baseline: 1.0164x; 1.0164x over previous
//
#include <hip/hip_runtime.h>

// ---------------------------------------------------------------------------
// CausalAttention: B=8, S=2048, D=1024, fp32 in, fp32 out.
// Round 10: r8 data layout + proper counted-lgkm sub-phase schedule.
//   r9 post-mortem: lgkm(0) full-drain at phase top (reads issued after the
//   previous barrier) exposed the whole LDS service latency. m201-template
//   fix: issue NEXT sub-tile's ds_reads BEFORE the barrier-adjacent wait and
//   gate the MFMA on a COUNTED lgkmcnt(N) (N = reads just issued), so only
//   the one-phase-old operand reads must have landed.
//   - BM=BN=256, BK=32, 8 waves (2Mx4N), 512 thr; LDS 128KB = 4 slots
//   - slot: A[256][32]h + B[256][32]h, coalesced glds (chunk u->row=u>>2),
//     both-sides XOR swizzle (r8-validated): source col c^((row>>1)&3),
//     same XOR on frag read -> 0 bank conflicts
//   - per K-tile: 2 sub-phases x 16 MFMA (aLo = wave rows 0-63, aHi 64-127)
//     phase: [vmcnt(8)|barrier|reads(next)|{stage}|lgkm(4/8)+schedbar|MFMA16]
//   - schedule (proven in-line): STAGE(t+3) at (t,0); reads a0/b(t+1) at
//     (t,1), aHi(t) at (t,0); slot t&3 sealed by (t-1,1)'s lgkm+barrier.
//     vmcnt steady 8, tail 8/8/8/4/4/0. b regs by tile parity (bE/bO).
//   - scores: fully-masked tiles write NOTHING; softmax reads/writes only
//     the tile-aligned valid prefix (pv reads exactly k<(by+1)*256).
//   ws: Q 32 | K 32 | Vt 32 | Sc 64  (xh@Sc+0 32MB, Wh@Sc+32MB 6MB)
// ---------------------------------------------------------------------------

typedef _Float16 v8h __attribute__((ext_vector_type(8)));
typedef _Float16 v4h __attribute__((ext_vector_type(4)));
typedef float    v4f __attribute__((ext_vector_type(4)));

#define BM 256
#define BN 256

__device__ __forceinline__ void async16(const _Float16* g, _Float16* l) {
  __builtin_amdgcn_global_load_lds(
      (__attribute__((address_space(1))) void*)(void*)g,
      (__attribute__((address_space(3))) void*)l, 16, 0, 0);
}

__device__ __forceinline__ void rd_a(const _Float16* U, int offA0, int base,
                                     v8h a[4]) {
#pragma unroll
  for (int i = 0; i < 4; ++i) a[i] = *(const v8h*)(U + offA0 + (base + i) * 512);
}
__device__ __forceinline__ void rd_b(const _Float16* U, int offB0, v8h b[4]) {
#pragma unroll
  for (int j = 0; j < 4; ++j) b[j] = *(const v8h*)(U + offB0 + j * 512);
}

__device__ __forceinline__ void mfma16(const v8h a[4], const v8h b[4],
                                       v4f (*accr)[4]) {
  __builtin_amdgcn_s_setprio(1);
#pragma unroll
  for (int i = 0; i < 4; ++i)
#pragma unroll
    for (int j = 0; j < 4; ++j)
      accr[i][j] = __builtin_amdgcn_mfma_f32_16x16x32_f16(a[i], b[j],
                                                          accr[i][j], 0, 0, 0);
  __builtin_amdgcn_s_setprio(0);
}

#define VM8 asm volatile("s_waitcnt vmcnt(8)" ::: "memory")
#define VM4 asm volatile("s_waitcnt vmcnt(4)" ::: "memory")
#define VM0 asm volatile("s_waitcnt vmcnt(0)" ::: "memory")
#define LG8                                                                  \
  asm volatile("s_waitcnt lgkmcnt(8)" ::: "memory");                         \
  __builtin_amdgcn_sched_barrier(0)
#define LG4                                                                  \
  asm volatile("s_waitcnt lgkmcnt(4)" ::: "memory");                         \
  __builtin_amdgcn_sched_barrier(0)
#define LG0                                                                  \
  asm volatile("s_waitcnt lgkmcnt(0)" ::: "memory");                         \
  __builtin_amdgcn_sched_barrier(0)
#define BAR __builtin_amdgcn_s_barrier()

// ---------------------------------------------------------------------------
// Shared GEMM loop, counted-lgkm sub-phase schedule.  NKT even, >= 8.
// ---------------------------------------------------------------------------
__device__ __forceinline__ void gemm_loop(const _Float16* Ab, int lda,
                                          const _Float16* Bb, int ldb,
                                          int NKT, _Float16* lds,
                                          int w, int lane, int wr, int wc,
                                          int lr, int quad, v4f acc[8][4]) {
  // frag offsets (elements); XOR term invariant under row+=16 [r8-validated]
  const int offA0 = (wr + lr) * 32 + ((quad ^ (((wr + lr) >> 1) & 3)) * 8);
  const int offB0 = 8192 + (wc + lr) * 32 + ((quad ^ (((wc + lr) >> 1) & 3)) * 8);

  // staging: chunk u = w*128 + g*64 + lane; row=u>>2, c=u&3; pre-swizzled
  // global source col = c ^ ((row>>1)&3)  (involution).
  const int u0 = w * 128 + lane;
  const int u1 = u0 + 64;
  const int r0 = u0 >> 2, c0 = (u0 & 3) ^ ((r0 >> 1) & 3);
  const int r1 = u1 >> 2, c1 = (u1 & 3) ^ ((r1 >> 1) & 3);
  const _Float16* pA0 = Ab + (size_t)r0 * lda + c0 * 8;
  const _Float16* pA1 = Ab + (size_t)r1 * lda + c1 * 8;
  const _Float16* pB0 = Bb + (size_t)r0 * ldb + c0 * 8;
  const _Float16* pB1 = Bb + (size_t)r1 * ldb + c1 * 8;
  const int dA0 = (w * 128) * 8;
  const int dA1 = (w * 128 + 64) * 8;

#define STAGE(T)                                                             \
  do {                                                                       \
    _Float16* Ld = lds + ((T) & 3) * 16384;                                  \
    async16(pA0 + (T) * 32, Ld + dA0);                                       \
    async16(pB0 + (T) * 32, Ld + 8192 + dA0);                                \
    async16(pA1 + (T) * 32, Ld + dA1);                                       \
    async16(pB1 + (T) * 32, Ld + 8192 + dA1);                                \
  } while (0)
#define SL(T) (lds + ((T) & 3) * 16384)

  v8h aLo[4], aHi[4], bE[4], bO[4];

  // prologue: stage tiles 0..2; confirm tile 0; read aLo(0), bE(0).
  STAGE(0);
  STAGE(1);
  STAGE(2);
  VM8;
  BAR;
  rd_a(SL(0), offA0, 0, aLo);
  rd_b(SL(0), offB0, bE);

  for (int t2 = 0; t2 < NKT - 4; t2 += 2) {
    // (t2,0): read aHi(t2); stage t2+3; MFMA aLo x bE -> acc[0..3]
    VM8; BAR;
    rd_a(SL(t2), offA0, 4, aHi);
    STAGE(t2 + 3);
    LG4; mfma16(aLo, bE, &acc[0]);
    // (t2,1): read aLo(t2+1), bO(t2+1); MFMA aHi x bE -> acc[4..7]
    VM8; BAR;
    rd_a(SL(t2 + 1), offA0, 0, aLo);
    rd_b(SL(t2 + 1), offB0, bO);
    LG8; mfma16(aHi, bE, &acc[4]);
    // (t2+1,0): read aHi(t2+1); stage t2+4; MFMA aLo x bO
    VM8; BAR;
    rd_a(SL(t2 + 1), offA0, 4, aHi);
    STAGE(t2 + 4);
    LG4; mfma16(aLo, bO, &acc[0]);
    // (t2+1,1): read aLo(t2+2), bE(t2+2); MFMA aHi x bO
    VM8; BAR;
    rd_a(SL(t2 + 2), offA0, 0, aLo);
    rd_b(SL(t2 + 2), offB0, bE);
    LG8; mfma16(aHi, bO, &acc[4]);
  }

  // tail pair 1: t2 = NKT-4  (stage NKT-1; vmcnt 8/8/8/4)
  VM8; BAR;
  rd_a(SL(NKT - 4), offA0, 4, aHi);
  STAGE(NKT - 1);
  LG4; mfma16(aLo, bE, &acc[0]);
  VM8; BAR;
  rd_a(SL(NKT - 3), offA0, 0, aLo);
  rd_b(SL(NKT - 3), offB0, bO);
  LG8; mfma16(aHi, bE, &acc[4]);
  VM8; BAR;
  rd_a(SL(NKT - 3), offA0, 4, aHi);
  LG4; mfma16(aLo, bO, &acc[0]);
  VM4; BAR;
  rd_a(SL(NKT - 2), offA0, 0, aLo);
  rd_b(SL(NKT - 2), offB0, bE);
  LG8; mfma16(aHi, bO, &acc[4]);

  // tail pair 2: t2 = NKT-2  (no stages; vmcnt 4/0/-/-)
  VM4; BAR;
  rd_a(SL(NKT - 2), offA0, 4, aHi);
  LG4; mfma16(aLo, bE, &acc[0]);
  VM0; BAR;
  rd_a(SL(NKT - 1), offA0, 0, aLo);
  rd_b(SL(NKT - 1), offB0, bO);
  LG8; mfma16(aHi, bE, &acc[4]);
  BAR;
  rd_a(SL(NKT - 1), offA0, 4, aHi);
  LG4; mfma16(aLo, bO, &acc[0]);
  LG0; mfma16(aHi, bO, &acc[4]);
#undef STAGE
#undef SL
}

// Bijective XCD-aware swizzle of the per-z 2D grid (requires nwg%8==0:
// proj 768, scores 64, pv 32 — all divisible).
__device__ __forceinline__ void grid_swz(int& bx, int& by) {
  const int gx = gridDim.x;
  const int n = gx * gridDim.y;
  const int f = blockIdx.x + blockIdx.y * gx;
  const int s = (f & 7) * (n >> 3) + (f >> 3);
  bx = s % gx;
  by = s / gx;
}

// ---------------------------------------------------------------------------
// fp32 -> fp16, 8 elems/thread.
// ---------------------------------------------------------------------------
__global__ __launch_bounds__(256)
void cvt_f16(const float* __restrict__ src, _Float16* __restrict__ dst) {
  const int i = (blockIdx.x * 256 + threadIdx.x) * 8;
  float4 a = *(const float4*)(src + i);
  float4 b = *(const float4*)(src + i + 4);
  v8h o = {(_Float16)a.x, (_Float16)a.y, (_Float16)a.z, (_Float16)a.w,
           (_Float16)b.x, (_Float16)b.y, (_Float16)b.z, (_Float16)b.w};
  *(v8h*)(dst + i) = o;
}

// ---------------------------------------------------------------------------
// Projection: C[m][n] = X[m][:] . W[n][:], n in [0,3072) packed Q|K|V.
// Q,K stored [16384][1024]; V transposed Vt[b][d][s].
// ---------------------------------------------------------------------------
__global__ __launch_bounds__(512, 2)
void proj_gemm(const _Float16* __restrict__ X, const _Float16* __restrict__ W,
               _Float16* __restrict__ Qb, _Float16* __restrict__ Kb,
               _Float16* __restrict__ Vt) {
  __shared__ _Float16 lds[65536];
  const int tid = threadIdx.x;
  int bx, by;
  grid_swz(bx, by);
  const int n0 = bx * BN, m0 = by * BM;
  const int which = n0 >> 10;                    // 0=Q 1=K 2=V, block-uniform
  const int nw = n0 & 1023;

  const int lane = tid & 63, w = tid >> 6;
  const int wr = (w >> 2) * 128, wc = (w & 3) * 64;
  const int lr = lane & 15, quad = lane >> 4;

  v4f acc[8][4];
#pragma unroll
  for (int i = 0; i < 8; ++i)
#pragma unroll
    for (int j = 0; j < 4; ++j) acc[i][j] = (v4f){0.f, 0.f, 0.f, 0.f};

  gemm_loop(X + (size_t)m0 * 1024, 1024, W + (size_t)n0 * 1024, 1024,
            32, lds, w, lane, wr, wc, lr, quad, acc);

  // C/D layout: col = lane&15, row = quad*4 + reg  [validated r4]
#pragma unroll
  for (int i = 0; i < 8; ++i) {
    const int r0 = m0 + wr + i * 16 + quad * 4;
#pragma unroll
    for (int j = 0; j < 4; ++j) {
      const int cl = wc + j * 16 + lr;
      if (which < 2) {
        _Float16* dst = (which == 0) ? Qb : Kb;
        const int col = nw + cl;
#pragma unroll
        for (int rg = 0; rg < 4; ++rg)
          dst[(size_t)(r0 + rg) * 1024 + col] = (_Float16)acc[i][j][rg];
      } else {
        const int d = nw + cl;
        const int b = r0 >> 11, s = r0 & 2047;   // 4 rows stay in-batch
        v4h o = {(_Float16)acc[i][j][0], (_Float16)acc[i][j][1],
                 (_Float16)acc[i][j][2], (_Float16)acc[i][j][3]};
        *(v4h*)(Vt + (size_t)b * 1024 * 2048 + (size_t)d * 2048 + s) = o;
      }
    }
  }
}

// ---------------------------------------------------------------------------
// Scores: Sc[b][q][k] = Q[b][q][:].K[b][k][:] (f16 raw), -inf where k > q
// within the diagonal tile.  Fully-masked tiles (bx>by) write NOTHING:
// softmax/pv never touch k >= (q/256+1)*256.
// ---------------------------------------------------------------------------
__global__ __launch_bounds__(512, 2)
void scores_gemm(const _Float16* __restrict__ Q, const _Float16* __restrict__ K,
                 _Float16* __restrict__ Sc) {
  __shared__ _Float16 lds[65536];
  const int tid = threadIdx.x;
  int bx, by;
  grid_swz(bx, by);
  const int bz = blockIdx.z;
  const int n0 = bx * BN, m0 = by * BM;
  _Float16* Cb = Sc + (size_t)bz * 2048 * 2048;

  if (bx > by) return;                           // fully masked: skip

  const _Float16* Qz = Q + (size_t)bz * 2048 * 1024;
  const _Float16* Kz = K + (size_t)bz * 2048 * 1024;

  const int lane = tid & 63, w = tid >> 6;
  const int wr = (w >> 2) * 128, wc = (w & 3) * 64;
  const int lr = lane & 15, quad = lane >> 4;

  v4f acc[8][4];
#pragma unroll
  for (int i = 0; i < 8; ++i)
#pragma unroll
    for (int j = 0; j < 4; ++j) acc[i][j] = (v4f){0.f, 0.f, 0.f, 0.f};

  gemm_loop(Qz + (size_t)m0 * 1024, 1024, Kz + (size_t)n0 * 1024, 1024,
            32, lds, w, lane, wr, wc, lr, quad, acc);

  const _Float16 ninf = (_Float16)(-__builtin_inff());
#pragma unroll
  for (int i = 0; i < 8; ++i) {
    const int r0 = m0 + wr + i * 16 + quad * 4;
#pragma unroll
    for (int j = 0; j < 4; ++j) {
      const int cc = n0 + wc + j * 16 + lr;
#pragma unroll
      for (int rg = 0; rg < 4; ++rg) {
        const int rr = r0 + rg;
        Cb[(size_t)rr * 2048 + cc] = (cc > rr) ? ninf : (_Float16)acc[i][j][rg];
      }
    }
  }
}

// ---------------------------------------------------------------------------
// Row softmax in place (f16), scale 1/32 inside exp.  Only the tile-aligned
// valid prefix [0, (q/256+1)*256) is read/written (pv reads exactly that).
// ---------------------------------------------------------------------------
__global__ __launch_bounds__(256)
void softmax_rows(_Float16* __restrict__ Sc) {
  _Float16* base = Sc + (size_t)blockIdx.x * 2048;
  const int q = blockIdx.x & 2047;
  const int ktile = ((q >> 8) + 1) << 8;
  const int tid = threadIdx.x;
  const int lane = tid & 63, w = tid >> 6;
  const bool active = tid * 8 < ktile;

  float f[8];
  if (active) {
    v8h pv = *(const v8h*)(base + tid * 8);
#pragma unroll
    for (int j = 0; j < 8; ++j) f[j] = (float)pv[j];
  } else {
#pragma unroll
    for (int j = 0; j < 8; ++j) f[j] = -__builtin_inff();
  }

  float mx = f[0];
#pragma unroll
  for (int j = 1; j < 8; ++j) mx = fmaxf(mx, f[j]);
#pragma unroll
  for (int off = 32; off; off >>= 1) mx = fmaxf(mx, __shfl_xor(mx, off));
  __shared__ float redm[4], reds[4];
  if (lane == 0) redm[w] = mx;
  __syncthreads();
  mx = fmaxf(fmaxf(redm[0], redm[1]), fmaxf(redm[2], redm[3]));

  const float scale = 0.03125f;                  // 1/sqrt(1024)
  float e[8], s = 0.f;
#pragma unroll
  for (int j = 0; j < 8; ++j) {
    e[j] = __expf((f[j] - mx) * scale);
    s += e[j];
  }
#pragma unroll
  for (int off = 32; off; off >>= 1) s += __shfl_xor(s, off);
  if (lane == 0) reds[w] = s;
  __syncthreads();
  s = reds[0] + reds[1] + reds[2] + reds[3];
  const float inv = 1.0f / s;
  if (active) {
    v8h pv;
#pragma unroll
    for (int j = 0; j < 8; ++j) pv[j] = (_Float16)(e[j] * inv);
    *(v8h*)(base + tid * 8) = pv;
  }
}

// ---------------------------------------------------------------------------
// Out (fp32): out[b][q][d] = sum_k P[b][q][k] * Vt[b][d][k]; K-loop causally
// truncated to (by+1)*256  -> NKT = (by+1)*8 >= 8 (even).
// ---------------------------------------------------------------------------
__global__ __launch_bounds__(512, 2)
void pv_gemm(const _Float16* __restrict__ P, const _Float16* __restrict__ Vt,
             float* __restrict__ Out) {
  __shared__ _Float16 lds[65536];
  const int tid = threadIdx.x;
  int bx, by;
  grid_swz(bx, by);
  const int bz = blockIdx.z;
  const int n0 = bx * BN, m0 = by * BM;
  const _Float16* Pb = P + (size_t)bz * 2048 * 2048;
  const _Float16* Vb = Vt + (size_t)bz * 1024 * 2048;
  float* Cb = Out + (size_t)bz * 2048 * 1024;

  const int lane = tid & 63, w = tid >> 6;
  const int wr = (w >> 2) * 128, wc = (w & 3) * 64;
  const int lr = lane & 15, quad = lane >> 4;

  v4f acc[8][4];
#pragma unroll
  for (int i = 0; i < 8; ++i)
#pragma unroll
    for (int j = 0; j < 4; ++j) acc[i][j] = (v4f){0.f, 0.f, 0.f, 0.f};

  gemm_loop(Pb + (size_t)m0 * 2048, 2048, Vb + (size_t)n0 * 2048, 2048,
            (by + 1) * 8, lds, w, lane, wr, wc, lr, quad, acc);

#pragma unroll
  for (int i = 0; i < 8; ++i) {
    const int r0 = m0 + wr + i * 16 + quad * 4;
#pragma unroll
    for (int j = 0; j < 4; ++j) {
      const int cc = n0 + wc + j * 16 + lr;
#pragma unroll
      for (int rg = 0; rg < 4; ++rg)
        Cb[(size_t)(r0 + rg) * 1024 + cc] = acc[i][j][rg];   // fp32 store
    }
  }
}

// ---------------------------------------------------------------------------
extern "C" void kernel_launch(void* const* d_in, const int* in_sizes, int n_in,
                              void* d_out, int out_size, void* d_ws, size_t ws_size,
                              hipStream_t stream) {
  const int B = 8, S = 2048, D = 1024;
  const int M = B * S;                           // 16384
  const float* x  = (const float*)d_in[0];
  const float* Wq = (const float*)d_in[1];
  const float* Wk = (const float*)d_in[2];
  const float* Wv = (const float*)d_in[3];
  float* out = (float*)d_out;

  // ws: Q 32MB | K 32MB | Vt 32MB | Sc 64MB (160 MB total, validated r4).
  // xh (32MB) and Wh (6MB) alias the head of Sc — dead before scores writes.
  char* ws = (char*)d_ws;
  _Float16* Qb = (_Float16*)ws;                          // [M][1024]
  _Float16* Kb = (_Float16*)(ws + (size_t)33554432);     // [M][1024]
  _Float16* Vt = (_Float16*)(ws + (size_t)67108864);     // [B][1024][2048]
  _Float16* Sc = (_Float16*)(ws + (size_t)100663296);    // [B][2048][2048]
  _Float16* xh = Sc;                                     // [M][1024]   (alias)
  _Float16* Wh = Sc + (size_t)M * D;                     // [3072][1024](alias)

  // 1) fp32 -> fp16 converts (memory-bound)
  cvt_f16<<<(M * D) / 2048, 256, 0, stream>>>(x, xh);
  cvt_f16<<<(D * D) / 2048, 256, 0, stream>>>(Wq, Wh);
  cvt_f16<<<(D * D) / 2048, 256, 0, stream>>>(Wk, Wh + (size_t)D * D);
  cvt_f16<<<(D * D) / 2048, 256, 0, stream>>>(Wv, Wh + (size_t)2 * D * D);

  // 2) QKV projection (counted-lgkm sub-phase GEMM)
  proj_gemm<<<dim3(12, M / BM, 1), 512, 0, stream>>>(xh, Wh, Qb, Kb, Vt);

  // 3) raw scores, causal; masked tiles untouched
  scores_gemm<<<dim3(S / BN, S / BM, B), 512, 0, stream>>>(Qb, Kb, Sc);

  // 4) softmax on valid prefix in place
  softmax_rows<<<B * S, 256, 0, stream>>>(Sc);

  // 5) out = P @ Vt, fp32 store
  pv_gemm<<<dim3(D / BN, S / BM, B), 512, 0, stream>>>(Sc, Vt, out);
}

// Round 6
// 393.649 us; speedup vs baseline: 1.0254x; 1.0088x over previous
//
#include <hip/hip_runtime.h>

// ---------------------------------------------------------------------------
// CausalAttention: B=8, S=2048, D=1024, fp32 in, fp32 out.
// Round 11: r10 data layout + EXACT m201 phase skeleton.
//   r10 post-mortem: reads issued after the barrier + counted-lgkm gate put
//   the read-issue+wait INSIDE the matrix-pipe window; lockstep waves drain
//   the pipe every phase (44% busy by cycle model, matches MfmaUtil).
//   m201 skeleton: reads+stage BEFORE BAR1 (LDS latency hides under barrier
//   sync), BAR1 -> lgkm(0) (free) -> pure 16-MFMA cluster -> BAR2. vmcnt
//   counted, once per K-tile, placed BEFORE a barrier so residency is
//   established for ALL waves.
//   - BM=BN=256, BK=32, 8 waves (2Mx4N), 512 thr; LDS 128KB = 4 slots
//   - slot: A[256][32]h + B[256][32]h, coalesced glds (chunk u->row=u>>2),
//     both-sides XOR swizzle (r8-validated): source col c^((row>>1)&3),
//     same XOR on frag read -> 0 bank conflicts
//   - schedule per K-tile t (2 phases, 2 barriers each):
//       (t,0): rd aLo(t)+b(t) [8 ds]; STAGE(t+3) [4 glds]; BAR; LG0; MFMA16
//              (acc[0..3]); BAR
//       (t,1): rd aHi(t) [4 ds]; VM4 (t<=NKT-4) / VM0 (t==NKT-3); BAR; LG0;
//              MFMA16 (acc[4..7]); BAR
//     residency: VM4@(t,1) leaves {t+2} outstanding => tile t+1 confirmed
//     before a barrier, read 2 phases later.  WAR: STAGE(t+3) -> slot
//     (t-1)&3 issues after (t-1,1) BAR2 (all waves' reads of t-1 drained by
//     their LG0).  vmcnt never 0 mid-loop.
//   - scores: masked tiles write nothing; softmax on tile-aligned prefix.
//   ws: Q 32 | K 32 | Vt 32 | Sc 64  (xh@Sc+0 32MB, Wh@Sc+32MB 6MB)
// ---------------------------------------------------------------------------

typedef _Float16 v8h __attribute__((ext_vector_type(8)));
typedef _Float16 v4h __attribute__((ext_vector_type(4)));
typedef float    v4f __attribute__((ext_vector_type(4)));

#define BM 256
#define BN 256

__device__ __forceinline__ void async16(const _Float16* g, _Float16* l) {
  __builtin_amdgcn_global_load_lds(
      (__attribute__((address_space(1))) void*)(void*)g,
      (__attribute__((address_space(3))) void*)l, 16, 0, 0);
}

__device__ __forceinline__ void rd_a(const _Float16* U, int offA0, int base,
                                     v8h a[4]) {
#pragma unroll
  for (int i = 0; i < 4; ++i) a[i] = *(const v8h*)(U + offA0 + (base + i) * 512);
}
__device__ __forceinline__ void rd_b(const _Float16* U, int offB0, v8h b[4]) {
#pragma unroll
  for (int j = 0; j < 4; ++j) b[j] = *(const v8h*)(U + offB0 + j * 512);
}

__device__ __forceinline__ void mfma16(const v8h a[4], const v8h b[4],
                                       v4f (*accr)[4]) {
  __builtin_amdgcn_s_setprio(1);
#pragma unroll
  for (int i = 0; i < 4; ++i)
#pragma unroll
    for (int j = 0; j < 4; ++j)
      accr[i][j] = __builtin_amdgcn_mfma_f32_16x16x32_f16(a[i], b[j],
                                                          accr[i][j], 0, 0, 0);
  __builtin_amdgcn_s_setprio(0);
}

#define VM8 asm volatile("s_waitcnt vmcnt(8)" ::: "memory")
#define VM4 asm volatile("s_waitcnt vmcnt(4)" ::: "memory")
#define VM0 asm volatile("s_waitcnt vmcnt(0)" ::: "memory")
// lgkm(0) AFTER the barrier: reads were issued pre-barrier, their latency
// hides under barrier sync.  sched_barrier stops MFMA hoisting (rule #18).
#define LG0                                                                  \
  asm volatile("s_waitcnt lgkmcnt(0)" ::: "memory");                         \
  __builtin_amdgcn_sched_barrier(0)
#define BAR __builtin_amdgcn_s_barrier()

// ---------------------------------------------------------------------------
// Shared GEMM loop, m201 two-barrier phase skeleton.  NKT >= 8.
// ---------------------------------------------------------------------------
__device__ __forceinline__ void gemm_loop(const _Float16* Ab, int lda,
                                          const _Float16* Bb, int ldb,
                                          int NKT, _Float16* lds,
                                          int w, int lane, int wr, int wc,
                                          int lr, int quad, v4f acc[8][4]) {
  // frag offsets (elements); XOR term invariant under row+=16 [r8-validated]
  const int offA0 = (wr + lr) * 32 + ((quad ^ (((wr + lr) >> 1) & 3)) * 8);
  const int offB0 = 8192 + (wc + lr) * 32 + ((quad ^ (((wc + lr) >> 1) & 3)) * 8);

  // staging: chunk u = w*128 + g*64 + lane; row=u>>2, c=u&3; pre-swizzled
  // global source col = c ^ ((row>>1)&3)  (involution).
  const int u0 = w * 128 + lane;
  const int u1 = u0 + 64;
  const int r0 = u0 >> 2, c0 = (u0 & 3) ^ ((r0 >> 1) & 3);
  const int r1 = u1 >> 2, c1 = (u1 & 3) ^ ((r1 >> 1) & 3);
  const _Float16* pA0 = Ab + (size_t)r0 * lda + c0 * 8;
  const _Float16* pA1 = Ab + (size_t)r1 * lda + c1 * 8;
  const _Float16* pB0 = Bb + (size_t)r0 * ldb + c0 * 8;
  const _Float16* pB1 = Bb + (size_t)r1 * ldb + c1 * 8;
  const int dA0 = (w * 128) * 8;
  const int dA1 = (w * 128 + 64) * 8;

#define STAGE(T)                                                             \
  do {                                                                       \
    _Float16* Ld = lds + ((T) & 3) * 16384;                                  \
    async16(pA0 + (T) * 32, Ld + dA0);                                       \
    async16(pB0 + (T) * 32, Ld + 8192 + dA0);                                \
    async16(pA1 + (T) * 32, Ld + dA1);                                       \
    async16(pB1 + (T) * 32, Ld + 8192 + dA1);                                \
  } while (0)
#define SL(T) (lds + ((T) & 3) * 16384)

  v8h aLo[4], aHi[4], bC[4];

  // prologue: stage tiles 0..2 (12 glds); VM8 confirms tile 0 ({1,2} stay
  // in flight); barrier publishes residency to all waves.
  STAGE(0);
  STAGE(1);
  STAGE(2);
  VM8;
  BAR;

  for (int t = 0; t < NKT; ++t) {
    // ---- phase (t,0)
    rd_a(SL(t), offA0, 0, aLo);
    rd_b(SL(t), offB0, bC);
    if (t + 3 < NKT) STAGE(t + 3);
    BAR;
    LG0;
    mfma16(aLo, bC, &acc[0]);
    BAR;
    // ---- phase (t,1)
    rd_a(SL(t), offA0, 4, aHi);
    if (t <= NKT - 4) {
      VM4;                     // confirms tile t+2 (leaves {t+3} in flight)
    } else if (t == NKT - 3) {
      VM0;                     // confirms last tile NKT-1
    }
    BAR;
    LG0;
    mfma16(aHi, bC, &acc[4]);
    BAR;
  }
#undef STAGE
#undef SL
}

// Bijective XCD-aware swizzle of the per-z 2D grid (requires nwg%8==0:
// proj 768, scores 64, pv 32 — all divisible).
__device__ __forceinline__ void grid_swz(int& bx, int& by) {
  const int gx = gridDim.x;
  const int n = gx * gridDim.y;
  const int f = blockIdx.x + blockIdx.y * gx;
  const int s = (f & 7) * (n >> 3) + (f >> 3);
  bx = s % gx;
  by = s / gx;
}

// ---------------------------------------------------------------------------
// fp32 -> fp16, 8 elems/thread.
// ---------------------------------------------------------------------------
__global__ __launch_bounds__(256)
void cvt_f16(const float* __restrict__ src, _Float16* __restrict__ dst) {
  const int i = (blockIdx.x * 256 + threadIdx.x) * 8;
  float4 a = *(const float4*)(src + i);
  float4 b = *(const float4*)(src + i + 4);
  v8h o = {(_Float16)a.x, (_Float16)a.y, (_Float16)a.z, (_Float16)a.w,
           (_Float16)b.x, (_Float16)b.y, (_Float16)b.z, (_Float16)b.w};
  *(v8h*)(dst + i) = o;
}

// 3 weight matrices (1024x1024 each) in one launch; 512 blocks per matrix.
__global__ __launch_bounds__(256)
void cvt_f16_w(const float* __restrict__ Wq, const float* __restrict__ Wk,
               const float* __restrict__ Wv, _Float16* __restrict__ dst) {
  const int bid = blockIdx.x;
  const int m = bid >> 9;                        // 0,1,2
  const float* src = (m == 0) ? Wq : (m == 1) ? Wk : Wv;
  const int i = ((bid & 511) * 256 + threadIdx.x) * 8;
  float4 a = *(const float4*)(src + i);
  float4 b = *(const float4*)(src + i + 4);
  v8h o = {(_Float16)a.x, (_Float16)a.y, (_Float16)a.z, (_Float16)a.w,
           (_Float16)b.x, (_Float16)b.y, (_Float16)b.z, (_Float16)b.w};
  *(v8h*)(dst + (size_t)m * 1048576 + i) = o;
}

// ---------------------------------------------------------------------------
// Projection: C[m][n] = X[m][:] . W[n][:], n in [0,3072) packed Q|K|V.
// Q,K stored [16384][1024]; V transposed Vt[b][d][s].
// ---------------------------------------------------------------------------
__global__ __launch_bounds__(512, 2)
void proj_gemm(const _Float16* __restrict__ X, const _Float16* __restrict__ W,
               _Float16* __restrict__ Qb, _Float16* __restrict__ Kb,
               _Float16* __restrict__ Vt) {
  __shared__ _Float16 lds[65536];
  const int tid = threadIdx.x;
  int bx, by;
  grid_swz(bx, by);
  const int n0 = bx * BN, m0 = by * BM;
  const int which = n0 >> 10;                    // 0=Q 1=K 2=V, block-uniform
  const int nw = n0 & 1023;

  const int lane = tid & 63, w = tid >> 6;
  const int wr = (w >> 2) * 128, wc = (w & 3) * 64;
  const int lr = lane & 15, quad = lane >> 4;

  v4f acc[8][4];
#pragma unroll
  for (int i = 0; i < 8; ++i)
#pragma unroll
    for (int j = 0; j < 4; ++j) acc[i][j] = (v4f){0.f, 0.f, 0.f, 0.f};

  gemm_loop(X + (size_t)m0 * 1024, 1024, W + (size_t)n0 * 1024, 1024,
            32, lds, w, lane, wr, wc, lr, quad, acc);

  // C/D layout: col = lane&15, row = quad*4 + reg  [validated r4]
#pragma unroll
  for (int i = 0; i < 8; ++i) {
    const int r0 = m0 + wr + i * 16 + quad * 4;
#pragma unroll
    for (int j = 0; j < 4; ++j) {
      const int cl = wc + j * 16 + lr;
      if (which < 2) {
        _Float16* dst = (which == 0) ? Qb : Kb;
        const int col = nw + cl;
#pragma unroll
        for (int rg = 0; rg < 4; ++rg)
          dst[(size_t)(r0 + rg) * 1024 + col] = (_Float16)acc[i][j][rg];
      } else {
        const int d = nw + cl;
        const int b = r0 >> 11, s = r0 & 2047;   // 4 rows stay in-batch
        v4h o = {(_Float16)acc[i][j][0], (_Float16)acc[i][j][1],
                 (_Float16)acc[i][j][2], (_Float16)acc[i][j][3]};
        *(v4h*)(Vt + (size_t)b * 1024 * 2048 + (size_t)d * 2048 + s) = o;
      }
    }
  }
}

// ---------------------------------------------------------------------------
// Scores: Sc[b][q][k] = Q[b][q][:].K[b][k][:] (f16 raw), -inf where k > q
// within the diagonal tile.  Fully-masked tiles (bx>by) write NOTHING.
// ---------------------------------------------------------------------------
__global__ __launch_bounds__(512, 2)
void scores_gemm(const _Float16* __restrict__ Q, const _Float16* __restrict__ K,
                 _Float16* __restrict__ Sc) {
  __shared__ _Float16 lds[65536];
  const int tid = threadIdx.x;
  int bx, by;
  grid_swz(bx, by);
  const int bz = blockIdx.z;
  const int n0 = bx * BN, m0 = by * BM;
  _Float16* Cb = Sc + (size_t)bz * 2048 * 2048;

  if (bx > by) return;                           // fully masked: skip

  const _Float16* Qz = Q + (size_t)bz * 2048 * 1024;
  const _Float16* Kz = K + (size_t)bz * 2048 * 1024;

  const int lane = tid & 63, w = tid >> 6;
  const int wr = (w >> 2) * 128, wc = (w & 3) * 64;
  const int lr = lane & 15, quad = lane >> 4;

  v4f acc[8][4];
#pragma unroll
  for (int i = 0; i < 8; ++i)
#pragma unroll
    for (int j = 0; j < 4; ++j) acc[i][j] = (v4f){0.f, 0.f, 0.f, 0.f};

  gemm_loop(Qz + (size_t)m0 * 1024, 1024, Kz + (size_t)n0 * 1024, 1024,
            32, lds, w, lane, wr, wc, lr, quad, acc);

  const _Float16 ninf = (_Float16)(-__builtin_inff());
#pragma unroll
  for (int i = 0; i < 8; ++i) {
    const int r0 = m0 + wr + i * 16 + quad * 4;
#pragma unroll
    for (int j = 0; j < 4; ++j) {
      const int cc = n0 + wc + j * 16 + lr;
#pragma unroll
      for (int rg = 0; rg < 4; ++rg) {
        const int rr = r0 + rg;
        Cb[(size_t)rr * 2048 + cc] = (cc > rr) ? ninf : (_Float16)acc[i][j][rg];
      }
    }
  }
}

// ---------------------------------------------------------------------------
// Row softmax in place (f16), scale 1/32 inside exp.  Only the tile-aligned
// valid prefix [0, (q/256+1)*256) is read/written (pv reads exactly that).
// ---------------------------------------------------------------------------
__global__ __launch_bounds__(256)
void softmax_rows(_Float16* __restrict__ Sc) {
  _Float16* base = Sc + (size_t)blockIdx.x * 2048;
  const int q = blockIdx.x & 2047;
  const int ktile = ((q >> 8) + 1) << 8;
  const int tid = threadIdx.x;
  const int lane = tid & 63, w = tid >> 6;
  const bool active = tid * 8 < ktile;

  float f[8];
  if (active) {
    v8h pv = *(const v8h*)(base + tid * 8);
#pragma unroll
    for (int j = 0; j < 8; ++j) f[j] = (float)pv[j];
  } else {
#pragma unroll
    for (int j = 0; j < 8; ++j) f[j] = -__builtin_inff();
  }

  float mx = f[0];
#pragma unroll
  for (int j = 1; j < 8; ++j) mx = fmaxf(mx, f[j]);
#pragma unroll
  for (int off = 32; off; off >>= 1) mx = fmaxf(mx, __shfl_xor(mx, off));
  __shared__ float redm[4], reds[4];
  if (lane == 0) redm[w] = mx;
  __syncthreads();
  mx = fmaxf(fmaxf(redm[0], redm[1]), fmaxf(redm[2], redm[3]));

  const float scale = 0.03125f;                  // 1/sqrt(1024)
  float e[8], s = 0.f;
#pragma unroll
  for (int j = 0; j < 8; ++j) {
    e[j] = __expf((f[j] - mx) * scale);
    s += e[j];
  }
#pragma unroll
  for (int off = 32; off; off >>= 1) s += __shfl_xor(s, off);
  if (lane == 0) reds[w] = s;
  __syncthreads();
  s = reds[0] + reds[1] + reds[2] + reds[3];
  const float inv = 1.0f / s;
  if (active) {
    v8h pv;
#pragma unroll
    for (int j = 0; j < 8; ++j) pv[j] = (_Float16)(e[j] * inv);
    *(v8h*)(base + tid * 8) = pv;
  }
}

// ---------------------------------------------------------------------------
// Out (fp32): out[b][q][d] = sum_k P[b][q][k] * Vt[b][d][k]; K-loop causally
// truncated to (by+1)*256  -> NKT = (by+1)*8 >= 8.
// ---------------------------------------------------------------------------
__global__ __launch_bounds__(512, 2)
void pv_gemm(const _Float16* __restrict__ P, const _Float16* __restrict__ Vt,
             float* __restrict__ Out) {
  __shared__ _Float16 lds[65536];
  const int tid = threadIdx.x;
  int bx, by;
  grid_swz(bx, by);
  const int bz = blockIdx.z;
  const int n0 = bx * BN, m0 = by * BM;
  const _Float16* Pb = P + (size_t)bz * 2048 * 2048;
  const _Float16* Vb = Vt + (size_t)bz * 1024 * 2048;
  float* Cb = Out + (size_t)bz * 2048 * 1024;

  const int lane = tid & 63, w = tid >> 6;
  const int wr = (w >> 2) * 128, wc = (w & 3) * 64;
  const int lr = lane & 15, quad = lane >> 4;

  v4f acc[8][4];
#pragma unroll
  for (int i = 0; i < 8; ++i)
#pragma unroll
    for (int j = 0; j < 4; ++j) acc[i][j] = (v4f){0.f, 0.f, 0.f, 0.f};

  gemm_loop(Pb + (size_t)m0 * 2048, 2048, Vb + (size_t)n0 * 2048, 2048,
            (by + 1) * 8, lds, w, lane, wr, wc, lr, quad, acc);

#pragma unroll
  for (int i = 0; i < 8; ++i) {
    const int r0 = m0 + wr + i * 16 + quad * 4;
#pragma unroll
    for (int j = 0; j < 4; ++j) {
      const int cc = n0 + wc + j * 16 + lr;
#pragma unroll
      for (int rg = 0; rg < 4; ++rg)
        Cb[(size_t)(r0 + rg) * 1024 + cc] = acc[i][j][rg];   // fp32 store
    }
  }
}

// ---------------------------------------------------------------------------
extern "C" void kernel_launch(void* const* d_in, const int* in_sizes, int n_in,
                              void* d_out, int out_size, void* d_ws, size_t ws_size,
                              hipStream_t stream) {
  const int B = 8, S = 2048, D = 1024;
  const int M = B * S;                           // 16384
  const float* x  = (const float*)d_in[0];
  const float* Wq = (const float*)d_in[1];
  const float* Wk = (const float*)d_in[2];
  const float* Wv = (const float*)d_in[3];
  float* out = (float*)d_out;

  // ws: Q 32MB | K 32MB | Vt 32MB | Sc 64MB (160 MB total, validated r4).
  // xh (32MB) and Wh (6MB) alias the head of Sc — dead before scores writes.
  char* ws = (char*)d_ws;
  _Float16* Qb = (_Float16*)ws;                          // [M][1024]
  _Float16* Kb = (_Float16*)(ws + (size_t)33554432);     // [M][1024]
  _Float16* Vt = (_Float16*)(ws + (size_t)67108864);     // [B][1024][2048]
  _Float16* Sc = (_Float16*)(ws + (size_t)100663296);    // [B][2048][2048]
  _Float16* xh = Sc;                                     // [M][1024]   (alias)
  _Float16* Wh = Sc + (size_t)M * D;                     // [3072][1024](alias)

  // 1) fp32 -> fp16 converts (memory-bound)
  cvt_f16<<<(M * D) / 2048, 256, 0, stream>>>(x, xh);
  cvt_f16_w<<<1536, 256, 0, stream>>>(Wq, Wk, Wv, Wh);

  // 2) QKV projection (m201-skeleton GEMM)
  proj_gemm<<<dim3(12, M / BM, 1), 512, 0, stream>>>(xh, Wh, Qb, Kb, Vt);

  // 3) raw scores, causal; masked tiles untouched
  scores_gemm<<<dim3(S / BN, S / BM, B), 512, 0, stream>>>(Qb, Kb, Sc);

  // 4) softmax on valid prefix in place
  softmax_rows<<<B * S, 256, 0, stream>>>(Sc);

  // 5) out = P @ Vt, fp32 store
  pv_gemm<<<dim3(D / BN, S / BM, B), 512, 0, stream>>>(Sc, Vt, out);
}

// Round 8
// 385.901 us; speedup vs baseline: 1.0460x; 1.0201x over previous
//
#include <hip/hip_runtime.h>

// ---------------------------------------------------------------------------
// CausalAttention: B=8, S=2048, D=1024, fp32 in, fp32 out.
// Round 13: r12 resubmit with the ONE unsafe construct hardened — the float
// sqrtf triangular-index decode in scores_gemm is replaced by an exact
// integer loop (a mis-decode would OOB-write past Sc -> page fault ->
// "container failed twice", the r12 failure signature).  All else = r12:
//   - proj kept at its best measured form (r10, 116 µs).
//   - scores: 128x128 tiles, 4 waves, 64KB LDS -> 2 blocks/CU; triangular
//     1D grid (only bx<=by tiles): 136 x 8 = 1088 uniform blocks.
//   - pv: same 128^2 core + antithetic pairing (q-tile p and 15-p in one
//     block): every block does exactly 68 K-tiles; 8x8x8 = 512 blocks = 2/CU
//     all-resident, zero skew.
//   - both: r8-validated skeleton [rd frags | counted VM | BAR | STAGE(t+3)
//     | MFMA16], 4 slots, coalesced glds, XOR bank swizzle (0 conflicts).
//   - softmax valid-prefix granularity 128.
//   ws: Q 32 | K 32 | Vt 32 | Sc 64  (xh@Sc+0 32MB, Wh@Sc+32MB 6MB)
// ---------------------------------------------------------------------------

typedef _Float16 v8h __attribute__((ext_vector_type(8)));
typedef _Float16 v4h __attribute__((ext_vector_type(4)));
typedef float    v4f __attribute__((ext_vector_type(4)));

#define BM 256
#define BN 256

__device__ __forceinline__ void async16(const _Float16* g, _Float16* l) {
  __builtin_amdgcn_global_load_lds(
      (__attribute__((address_space(1))) void*)(void*)g,
      (__attribute__((address_space(3))) void*)l, 16, 0, 0);
}

__device__ __forceinline__ void rd_a(const _Float16* U, int offA0, int base,
                                     v8h a[4]) {
#pragma unroll
  for (int i = 0; i < 4; ++i) a[i] = *(const v8h*)(U + offA0 + (base + i) * 512);
}
__device__ __forceinline__ void rd_b(const _Float16* U, int offB0, v8h b[4]) {
#pragma unroll
  for (int j = 0; j < 4; ++j) b[j] = *(const v8h*)(U + offB0 + j * 512);
}

__device__ __forceinline__ void mfma16(const v8h a[4], const v8h b[4],
                                       v4f (*accr)[4]) {
  __builtin_amdgcn_s_setprio(1);
#pragma unroll
  for (int i = 0; i < 4; ++i)
#pragma unroll
    for (int j = 0; j < 4; ++j)
      accr[i][j] = __builtin_amdgcn_mfma_f32_16x16x32_f16(a[i], b[j],
                                                          accr[i][j], 0, 0, 0);
  __builtin_amdgcn_s_setprio(0);
}

#define VM8 asm volatile("s_waitcnt vmcnt(8)" ::: "memory")
#define VM4 asm volatile("s_waitcnt vmcnt(4)" ::: "memory")
#define VM0 asm volatile("s_waitcnt vmcnt(0)" ::: "memory")
#define LG8                                                                  \
  asm volatile("s_waitcnt lgkmcnt(8)" ::: "memory");                         \
  __builtin_amdgcn_sched_barrier(0)
#define LG4                                                                  \
  asm volatile("s_waitcnt lgkmcnt(4)" ::: "memory");                         \
  __builtin_amdgcn_sched_barrier(0)
#define LG0                                                                  \
  asm volatile("s_waitcnt lgkmcnt(0)" ::: "memory");                         \
  __builtin_amdgcn_sched_barrier(0)
#define BAR __builtin_amdgcn_s_barrier()
#define SBAR __builtin_amdgcn_sched_barrier(0)

// ---------------------------------------------------------------------------
// 256^2 / 8-wave GEMM loop (r10 form, best measured: proj 116 µs).
// ---------------------------------------------------------------------------
__device__ __forceinline__ void gemm_loop(const _Float16* Ab, int lda,
                                          const _Float16* Bb, int ldb,
                                          int NKT, _Float16* lds,
                                          int w, int lane, int wr, int wc,
                                          int lr, int quad, v4f acc[8][4]) {
  const int offA0 = (wr + lr) * 32 + ((quad ^ (((wr + lr) >> 1) & 3)) * 8);
  const int offB0 = 8192 + (wc + lr) * 32 + ((quad ^ (((wc + lr) >> 1) & 3)) * 8);

  const int u0 = w * 128 + lane;
  const int u1 = u0 + 64;
  const int r0 = u0 >> 2, c0 = (u0 & 3) ^ ((r0 >> 1) & 3);
  const int r1 = u1 >> 2, c1 = (u1 & 3) ^ ((r1 >> 1) & 3);
  const _Float16* pA0 = Ab + (size_t)r0 * lda + c0 * 8;
  const _Float16* pA1 = Ab + (size_t)r1 * lda + c1 * 8;
  const _Float16* pB0 = Bb + (size_t)r0 * ldb + c0 * 8;
  const _Float16* pB1 = Bb + (size_t)r1 * ldb + c1 * 8;
  const int dA0 = (w * 128) * 8;
  const int dA1 = (w * 128 + 64) * 8;

#define STAGE(T)                                                             \
  do {                                                                       \
    _Float16* Ld = lds + ((T) & 3) * 16384;                                  \
    async16(pA0 + (T) * 32, Ld + dA0);                                       \
    async16(pB0 + (T) * 32, Ld + 8192 + dA0);                                \
    async16(pA1 + (T) * 32, Ld + dA1);                                       \
    async16(pB1 + (T) * 32, Ld + 8192 + dA1);                                \
  } while (0)
#define SL(T) (lds + ((T) & 3) * 16384)

  v8h aLo[4], aHi[4], bE[4], bO[4];

  STAGE(0);
  STAGE(1);
  STAGE(2);
  VM8;
  BAR;
  rd_a(SL(0), offA0, 0, aLo);
  rd_b(SL(0), offB0, bE);

  for (int t2 = 0; t2 < NKT - 4; t2 += 2) {
    VM8; BAR;
    rd_a(SL(t2), offA0, 4, aHi);
    STAGE(t2 + 3);
    LG4; mfma16(aLo, bE, &acc[0]);
    VM8; BAR;
    rd_a(SL(t2 + 1), offA0, 0, aLo);
    rd_b(SL(t2 + 1), offB0, bO);
    LG8; mfma16(aHi, bE, &acc[4]);
    VM8; BAR;
    rd_a(SL(t2 + 1), offA0, 4, aHi);
    STAGE(t2 + 4);
    LG4; mfma16(aLo, bO, &acc[0]);
    VM8; BAR;
    rd_a(SL(t2 + 2), offA0, 0, aLo);
    rd_b(SL(t2 + 2), offB0, bE);
    LG8; mfma16(aHi, bO, &acc[4]);
  }

  VM8; BAR;
  rd_a(SL(NKT - 4), offA0, 4, aHi);
  STAGE(NKT - 1);
  LG4; mfma16(aLo, bE, &acc[0]);
  VM8; BAR;
  rd_a(SL(NKT - 3), offA0, 0, aLo);
  rd_b(SL(NKT - 3), offB0, bO);
  LG8; mfma16(aHi, bE, &acc[4]);
  VM8; BAR;
  rd_a(SL(NKT - 3), offA0, 4, aHi);
  LG4; mfma16(aLo, bO, &acc[0]);
  VM4; BAR;
  rd_a(SL(NKT - 2), offA0, 0, aLo);
  rd_b(SL(NKT - 2), offB0, bE);
  LG8; mfma16(aHi, bO, &acc[4]);

  VM4; BAR;
  rd_a(SL(NKT - 2), offA0, 4, aHi);
  LG4; mfma16(aLo, bE, &acc[0]);
  VM0; BAR;
  rd_a(SL(NKT - 1), offA0, 0, aLo);
  rd_b(SL(NKT - 1), offB0, bO);
  LG8; mfma16(aHi, bE, &acc[4]);
  BAR;
  rd_a(SL(NKT - 1), offA0, 4, aHi);
  LG4; mfma16(aLo, bO, &acc[0]);
  LG0; mfma16(aHi, bO, &acc[4]);
#undef STAGE
#undef SL
}

// ---------------------------------------------------------------------------
// 128^2 / 4-wave GEMM loop (r8 skeleton at half scale).  NKT >= 4.
// LDS: 4 slots x (A[128][32] 8KB + B[128][32] 8KB) = 64KB.
// Wave grid 2x2 (wave tile 64x64), acc[4][4].
// ---------------------------------------------------------------------------
__device__ __forceinline__ void gemm128(const _Float16* Ab, int lda,
                                        const _Float16* Bb, int ldb,
                                        int NKT, _Float16* lds,
                                        int w, int lane, int wr, int wc,
                                        int lr, int quad, v4f acc[4][4]) {
  const int offA0 = (wr + lr) * 32 + ((quad ^ (((wr + lr) >> 1) & 3)) * 8);
  const int offB0 = 4096 + (wc + lr) * 32 + ((quad ^ (((wc + lr) >> 1) & 3)) * 8);

  // staging: 8KB per operand = 512 16B-units; unit u -> row u>>2, col u&3,
  // pre-swizzled global source col = (u&3) ^ ((row>>1)&3).  4 glds/wave.
  const int u0 = w * 128 + lane;
  const int u1 = u0 + 64;
  const int r0 = u0 >> 2, c0 = (u0 & 3) ^ ((r0 >> 1) & 3);
  const int r1 = u1 >> 2, c1 = (u1 & 3) ^ ((r1 >> 1) & 3);
  const _Float16* pA0 = Ab + (size_t)r0 * lda + c0 * 8;
  const _Float16* pA1 = Ab + (size_t)r1 * lda + c1 * 8;
  const _Float16* pB0 = Bb + (size_t)r0 * ldb + c0 * 8;
  const _Float16* pB1 = Bb + (size_t)r1 * ldb + c1 * 8;
  const int dA0 = (w * 128) * 8;
  const int dA1 = (w * 128 + 64) * 8;

#define STAGE(T)                                                             \
  do {                                                                       \
    _Float16* Ld = lds + ((T) & 3) * 8192;                                   \
    async16(pA0 + (T) * 32, Ld + dA0);                                       \
    async16(pA1 + (T) * 32, Ld + dA1);                                       \
    async16(pB0 + (T) * 32, Ld + 4096 + dA0);                                \
    async16(pB1 + (T) * 32, Ld + 4096 + dA1);                                \
  } while (0)

  // prologue: tiles 0..2 (12 glds); VM8 confirms tile 0; BAR publishes.
  STAGE(0);
  STAGE(1);
  STAGE(2);
  VM8;
  BAR;

  for (int t = 0; t < NKT; ++t) {
    const _Float16* U = lds + (t & 3) * 8192;
    v8h a[4], b[4];
    rd_a(U, offA0, 0, a);
    rd_b(U, offB0, b);
    // confirm tile t+1 (outstanding: {t+1}:4 {t+2}:4 -> VM4 drains t+1)
    if (t < NKT - 2) { VM4; } else { VM0; }
    BAR;
    SBAR;                       // keep STAGE below the barrier (WAR fence)
    if (t + 3 < NKT) STAGE(t + 3);  // slot (t+3)&3: old readers drained by
                                    // their pre-MFMA lgkm + this BAR
    LG0;                        // own frag reads landed (issued pre-BAR)
    mfma16(a, b, &acc[0]);
  }
#undef STAGE
}

// Bijective XCD-aware swizzle (proj grid 768 % 8 == 0).
__device__ __forceinline__ void grid_swz(int& bx, int& by) {
  const int gx = gridDim.x;
  const int n = gx * gridDim.y;
  const int f = blockIdx.x + blockIdx.y * gx;
  const int s = (f & 7) * (n >> 3) + (f >> 3);
  bx = s % gx;
  by = s / gx;
}

// ---------------------------------------------------------------------------
// fp32 -> fp16, 8 elems/thread.
// ---------------------------------------------------------------------------
__global__ __launch_bounds__(256)
void cvt_f16(const float* __restrict__ src, _Float16* __restrict__ dst) {
  const int i = (blockIdx.x * 256 + threadIdx.x) * 8;
  float4 a = *(const float4*)(src + i);
  float4 b = *(const float4*)(src + i + 4);
  v8h o = {(_Float16)a.x, (_Float16)a.y, (_Float16)a.z, (_Float16)a.w,
           (_Float16)b.x, (_Float16)b.y, (_Float16)b.z, (_Float16)b.w};
  *(v8h*)(dst + i) = o;
}

__global__ __launch_bounds__(256)
void cvt_f16_w(const float* __restrict__ Wq, const float* __restrict__ Wk,
               const float* __restrict__ Wv, _Float16* __restrict__ dst) {
  const int bid = blockIdx.x;
  const int m = bid >> 9;
  const float* src = (m == 0) ? Wq : (m == 1) ? Wk : Wv;
  const int i = ((bid & 511) * 256 + threadIdx.x) * 8;
  float4 a = *(const float4*)(src + i);
  float4 b = *(const float4*)(src + i + 4);
  v8h o = {(_Float16)a.x, (_Float16)a.y, (_Float16)a.z, (_Float16)a.w,
           (_Float16)b.x, (_Float16)b.y, (_Float16)b.z, (_Float16)b.w};
  *(v8h*)(dst + (size_t)m * 1048576 + i) = o;
}

// ---------------------------------------------------------------------------
// Projection (r10 form): C[m][n] = X[m][:].W[n][:], n packed Q|K|V.
// ---------------------------------------------------------------------------
__global__ __launch_bounds__(512, 2)
void proj_gemm(const _Float16* __restrict__ X, const _Float16* __restrict__ W,
               _Float16* __restrict__ Qb, _Float16* __restrict__ Kb,
               _Float16* __restrict__ Vt) {
  __shared__ _Float16 lds[65536];
  const int tid = threadIdx.x;
  int bx, by;
  grid_swz(bx, by);
  const int n0 = bx * BN, m0 = by * BM;
  const int which = n0 >> 10;
  const int nw = n0 & 1023;

  const int lane = tid & 63, w = tid >> 6;
  const int wr = (w >> 2) * 128, wc = (w & 3) * 64;
  const int lr = lane & 15, quad = lane >> 4;

  v4f acc[8][4];
#pragma unroll
  for (int i = 0; i < 8; ++i)
#pragma unroll
    for (int j = 0; j < 4; ++j) acc[i][j] = (v4f){0.f, 0.f, 0.f, 0.f};

  gemm_loop(X + (size_t)m0 * 1024, 1024, W + (size_t)n0 * 1024, 1024,
            32, lds, w, lane, wr, wc, lr, quad, acc);

#pragma unroll
  for (int i = 0; i < 8; ++i) {
    const int r0 = m0 + wr + i * 16 + quad * 4;
#pragma unroll
    for (int j = 0; j < 4; ++j) {
      const int cl = wc + j * 16 + lr;
      if (which < 2) {
        _Float16* dst = (which == 0) ? Qb : Kb;
        const int col = nw + cl;
#pragma unroll
        for (int rg = 0; rg < 4; ++rg)
          dst[(size_t)(r0 + rg) * 1024 + col] = (_Float16)acc[i][j][rg];
      } else {
        const int d = nw + cl;
        const int b = r0 >> 11, s = r0 & 2047;
        v4h o = {(_Float16)acc[i][j][0], (_Float16)acc[i][j][1],
                 (_Float16)acc[i][j][2], (_Float16)acc[i][j][3]};
        *(v4h*)(Vt + (size_t)b * 1024 * 2048 + (size_t)d * 2048 + s) = o;
      }
    }
  }
}

// ---------------------------------------------------------------------------
// Scores: 128x128 tiles, triangular grid — block x in [0,136) -> (by, bx<=by)
// via EXACT integer decode; block y = batch.  2 blocks/CU.  Diagonal tile
// masks cc>rr to -inf; strictly-upper tiles never launched.
// ---------------------------------------------------------------------------
__global__ __launch_bounds__(256, 2)
void scores_gemm(const _Float16* __restrict__ Q, const _Float16* __restrict__ K,
                 _Float16* __restrict__ Sc) {
  __shared__ _Float16 lds[32768];
  const int tid = threadIdx.x;
  const int t1d = blockIdx.x;                    // 0..135 lower-tri index
  const int bz = blockIdx.y;

  // exact integer triangular decode: by = max b with b*(b+1)/2 <= t1d
  int by = 0;
  while ((by + 1) * (by + 2) / 2 <= t1d) ++by;   // <= 15 iterations, uniform
  const int bx = t1d - by * (by + 1) / 2;        // 0..by

  const int m0 = by * 128, n0 = bx * 128;
  _Float16* Cb = Sc + (size_t)bz * 2048 * 2048;
  const _Float16* Qz = Q + (size_t)bz * 2048 * 1024;
  const _Float16* Kz = K + (size_t)bz * 2048 * 1024;

  const int lane = tid & 63, w = tid >> 6;
  const int wr = (w >> 1) * 64, wc = (w & 1) * 64;
  const int lr = lane & 15, quad = lane >> 4;

  v4f acc[4][4];
#pragma unroll
  for (int i = 0; i < 4; ++i)
#pragma unroll
    for (int j = 0; j < 4; ++j) acc[i][j] = (v4f){0.f, 0.f, 0.f, 0.f};

  gemm128(Qz + (size_t)m0 * 1024, 1024, Kz + (size_t)n0 * 1024, 1024,
          32, lds, w, lane, wr, wc, lr, quad, acc);

  const _Float16 ninf = (_Float16)(-__builtin_inff());
  const bool diag = (bx == by);
#pragma unroll
  for (int i = 0; i < 4; ++i) {
    const int r0 = m0 + wr + i * 16 + quad * 4;
#pragma unroll
    for (int j = 0; j < 4; ++j) {
      const int cc = n0 + wc + j * 16 + lr;
#pragma unroll
      for (int rg = 0; rg < 4; ++rg) {
        const int rr = r0 + rg;
        _Float16 v = (_Float16)acc[i][j][rg];
        Cb[(size_t)rr * 2048 + cc] = (diag && cc > rr) ? ninf : v;
      }
    }
  }
}

// ---------------------------------------------------------------------------
// Row softmax in place (f16); valid prefix [0, (q/128+1)*128).
// ---------------------------------------------------------------------------
__global__ __launch_bounds__(256)
void softmax_rows(_Float16* __restrict__ Sc) {
  _Float16* base = Sc + (size_t)blockIdx.x * 2048;
  const int q = blockIdx.x & 2047;
  const int ktile = ((q >> 7) + 1) << 7;
  const int tid = threadIdx.x;
  const int lane = tid & 63, w = tid >> 6;
  const bool active = tid * 8 < ktile;

  float f[8];
  if (active) {
    v8h pv = *(const v8h*)(base + tid * 8);
#pragma unroll
    for (int j = 0; j < 8; ++j) f[j] = (float)pv[j];
  } else {
#pragma unroll
    for (int j = 0; j < 8; ++j) f[j] = -__builtin_inff();
  }

  float mx = f[0];
#pragma unroll
  for (int j = 1; j < 8; ++j) mx = fmaxf(mx, f[j]);
#pragma unroll
  for (int off = 32; off; off >>= 1) mx = fmaxf(mx, __shfl_xor(mx, off));
  __shared__ float redm[4], reds[4];
  if (lane == 0) redm[w] = mx;
  __syncthreads();
  mx = fmaxf(fmaxf(redm[0], redm[1]), fmaxf(redm[2], redm[3]));

  const float scale = 0.03125f;                  // 1/sqrt(1024)
  float e[8], s = 0.f;
#pragma unroll
  for (int j = 0; j < 8; ++j) {
    e[j] = __expf((f[j] - mx) * scale);
    s += e[j];
  }
#pragma unroll
  for (int off = 32; off; off >>= 1) s += __shfl_xor(s, off);
  if (lane == 0) reds[w] = s;
  __syncthreads();
  s = reds[0] + reds[1] + reds[2] + reds[3];
  const float inv = 1.0f / s;
  if (active) {
    v8h pv;
#pragma unroll
    for (int j = 0; j < 8; ++j) pv[j] = (_Float16)(e[j] * inv);
    *(v8h*)(base + tid * 8) = pv;
  }
}

// ---------------------------------------------------------------------------
// Out (fp32): antithetic-paired PV.  Block (bx, p, bz) computes q-tile p
// (NKT=(p+1)*4) then q-tile 15-p (NKT=(16-p)*4): 68 K-tiles per block,
// perfectly uniform.  512 blocks = 2/CU, all resident.
// ---------------------------------------------------------------------------
__global__ __launch_bounds__(256, 2)
void pv_gemm(const _Float16* __restrict__ P, const _Float16* __restrict__ Vt,
             float* __restrict__ Out) {
  __shared__ _Float16 lds[32768];
  const int tid = threadIdx.x;
  const int bxx = blockIdx.x;                    // 0..7 (N-tile of 128)
  const int pair = blockIdx.y;                   // 0..7
  const int bz = blockIdx.z;
  const int n0 = bxx * 128;
  const _Float16* Pb = P + (size_t)bz * 2048 * 2048;
  const _Float16* Vb = Vt + (size_t)bz * 1024 * 2048;
  float* Cb = Out + (size_t)bz * 2048 * 1024;

  const int lane = tid & 63, w = tid >> 6;
  const int wr = (w >> 1) * 64, wc = (w & 1) * 64;
  const int lr = lane & 15, quad = lane >> 4;

#pragma unroll
  for (int part = 0; part < 2; ++part) {
    const int by = part ? (15 - pair) : pair;
    const int NKT = part ? ((16 - pair) * 4) : ((pair + 1) * 4);
    const int m0 = by * 128;

    v4f acc[4][4];
#pragma unroll
    for (int i = 0; i < 4; ++i)
#pragma unroll
      for (int j = 0; j < 4; ++j) acc[i][j] = (v4f){0.f, 0.f, 0.f, 0.f};

    gemm128(Pb + (size_t)m0 * 2048, 2048, Vb + (size_t)n0 * 2048, 2048,
            NKT, lds, w, lane, wr, wc, lr, quad, acc);

#pragma unroll
    for (int i = 0; i < 4; ++i) {
      const int r0 = m0 + wr + i * 16 + quad * 4;
#pragma unroll
      for (int j = 0; j < 4; ++j) {
        const int cc = n0 + wc + j * 16 + lr;
#pragma unroll
        for (int rg = 0; rg < 4; ++rg)
          Cb[(size_t)(r0 + rg) * 1024 + cc] = acc[i][j][rg];
      }
    }
    __syncthreads();   // all reads/stores of this part done before re-staging
  }
}

// ---------------------------------------------------------------------------
extern "C" void kernel_launch(void* const* d_in, const int* in_sizes, int n_in,
                              void* d_out, int out_size, void* d_ws, size_t ws_size,
                              hipStream_t stream) {
  const int B = 8, S = 2048, D = 1024;
  const int M = B * S;                           // 16384
  const float* x  = (const float*)d_in[0];
  const float* Wq = (const float*)d_in[1];
  const float* Wk = (const float*)d_in[2];
  const float* Wv = (const float*)d_in[3];
  float* out = (float*)d_out;

  char* ws = (char*)d_ws;
  _Float16* Qb = (_Float16*)ws;                          // [M][1024]
  _Float16* Kb = (_Float16*)(ws + (size_t)33554432);     // [M][1024]
  _Float16* Vt = (_Float16*)(ws + (size_t)67108864);     // [B][1024][2048]
  _Float16* Sc = (_Float16*)(ws + (size_t)100663296);    // [B][2048][2048]
  _Float16* xh = Sc;                                     // alias (dead later)
  _Float16* Wh = Sc + (size_t)M * D;                     // alias

  // 1) fp32 -> fp16 converts
  cvt_f16<<<(M * D) / 2048, 256, 0, stream>>>(x, xh);
  cvt_f16_w<<<1536, 256, 0, stream>>>(Wq, Wk, Wv, Wh);

  // 2) QKV projection (r10 256^2 GEMM)
  proj_gemm<<<dim3(12, M / BM, 1), 512, 0, stream>>>(xh, Wh, Qb, Kb, Vt);

  // 3) raw scores, triangular grid (1088 uniform blocks, 2/CU)
  scores_gemm<<<dim3(136, B, 1), 256, 0, stream>>>(Qb, Kb, Sc);

  // 4) softmax on 128-aligned valid prefix
  softmax_rows<<<B * S, 256, 0, stream>>>(Sc);

  // 5) out = P @ Vt, antithetic-paired balanced grid (512 blocks, 2/CU)
  pv_gemm<<<dim3(8, 8, B), 256, 0, stream>>>(Sc, Vt, out);
}

// Round 9
// 368.291 us; speedup vs baseline: 1.0960x; 1.0478x over previous
//
#include <hip/hip_runtime.h>

// ---------------------------------------------------------------------------
// CausalAttention: B=8, S=2048, D=1024, fp32 in, fp32 out.
// Round 14: r13 + ONE change (A/B on the core question): scores moves back
// to the 256^2 8-wave core (proj's measured-best gemm_loop) with a
// triangular 288-block launch (integer decode, no fill writes) and
// batch-chunk XCD swizzle (36 tiles = one batch triangle per XCD).
// pv / proj / softmax / cvt are byte-identical to r13 (385.9 µs baseline).
//   Rationale: r12/r13's 128^2 4-wave core delivered ~half the per-FLOP
//   rate of the 256^2 core by whole-pipeline accounting; this isolates it.
//   ws: Q 32 | K 32 | Vt 32 | Sc 64  (xh@Sc+0 32MB, Wh@Sc+32MB 6MB)
// ---------------------------------------------------------------------------

typedef _Float16 v8h __attribute__((ext_vector_type(8)));
typedef _Float16 v4h __attribute__((ext_vector_type(4)));
typedef float    v4f __attribute__((ext_vector_type(4)));

#define BM 256
#define BN 256

__device__ __forceinline__ void async16(const _Float16* g, _Float16* l) {
  __builtin_amdgcn_global_load_lds(
      (__attribute__((address_space(1))) void*)(void*)g,
      (__attribute__((address_space(3))) void*)l, 16, 0, 0);
}

__device__ __forceinline__ void rd_a(const _Float16* U, int offA0, int base,
                                     v8h a[4]) {
#pragma unroll
  for (int i = 0; i < 4; ++i) a[i] = *(const v8h*)(U + offA0 + (base + i) * 512);
}
__device__ __forceinline__ void rd_b(const _Float16* U, int offB0, v8h b[4]) {
#pragma unroll
  for (int j = 0; j < 4; ++j) b[j] = *(const v8h*)(U + offB0 + j * 512);
}

__device__ __forceinline__ void mfma16(const v8h a[4], const v8h b[4],
                                       v4f (*accr)[4]) {
  __builtin_amdgcn_s_setprio(1);
#pragma unroll
  for (int i = 0; i < 4; ++i)
#pragma unroll
    for (int j = 0; j < 4; ++j)
      accr[i][j] = __builtin_amdgcn_mfma_f32_16x16x32_f16(a[i], b[j],
                                                          accr[i][j], 0, 0, 0);
  __builtin_amdgcn_s_setprio(0);
}

#define VM8 asm volatile("s_waitcnt vmcnt(8)" ::: "memory")
#define VM4 asm volatile("s_waitcnt vmcnt(4)" ::: "memory")
#define VM0 asm volatile("s_waitcnt vmcnt(0)" ::: "memory")
#define LG8                                                                  \
  asm volatile("s_waitcnt lgkmcnt(8)" ::: "memory");                         \
  __builtin_amdgcn_sched_barrier(0)
#define LG4                                                                  \
  asm volatile("s_waitcnt lgkmcnt(4)" ::: "memory");                         \
  __builtin_amdgcn_sched_barrier(0)
#define LG0                                                                  \
  asm volatile("s_waitcnt lgkmcnt(0)" ::: "memory");                         \
  __builtin_amdgcn_sched_barrier(0)
#define BAR __builtin_amdgcn_s_barrier()
#define SBAR __builtin_amdgcn_sched_barrier(0)

// ---------------------------------------------------------------------------
// 256^2 / 8-wave GEMM loop (r10 form, measured best).
// ---------------------------------------------------------------------------
__device__ __forceinline__ void gemm_loop(const _Float16* Ab, int lda,
                                          const _Float16* Bb, int ldb,
                                          int NKT, _Float16* lds,
                                          int w, int lane, int wr, int wc,
                                          int lr, int quad, v4f acc[8][4]) {
  const int offA0 = (wr + lr) * 32 + ((quad ^ (((wr + lr) >> 1) & 3)) * 8);
  const int offB0 = 8192 + (wc + lr) * 32 + ((quad ^ (((wc + lr) >> 1) & 3)) * 8);

  const int u0 = w * 128 + lane;
  const int u1 = u0 + 64;
  const int r0 = u0 >> 2, c0 = (u0 & 3) ^ ((r0 >> 1) & 3);
  const int r1 = u1 >> 2, c1 = (u1 & 3) ^ ((r1 >> 1) & 3);
  const _Float16* pA0 = Ab + (size_t)r0 * lda + c0 * 8;
  const _Float16* pA1 = Ab + (size_t)r1 * lda + c1 * 8;
  const _Float16* pB0 = Bb + (size_t)r0 * ldb + c0 * 8;
  const _Float16* pB1 = Bb + (size_t)r1 * ldb + c1 * 8;
  const int dA0 = (w * 128) * 8;
  const int dA1 = (w * 128 + 64) * 8;

#define STAGE(T)                                                             \
  do {                                                                       \
    _Float16* Ld = lds + ((T) & 3) * 16384;                                  \
    async16(pA0 + (T) * 32, Ld + dA0);                                       \
    async16(pB0 + (T) * 32, Ld + 8192 + dA0);                                \
    async16(pA1 + (T) * 32, Ld + dA1);                                       \
    async16(pB1 + (T) * 32, Ld + 8192 + dA1);                                \
  } while (0)
#define SL(T) (lds + ((T) & 3) * 16384)

  v8h aLo[4], aHi[4], bE[4], bO[4];

  STAGE(0);
  STAGE(1);
  STAGE(2);
  VM8;
  BAR;
  rd_a(SL(0), offA0, 0, aLo);
  rd_b(SL(0), offB0, bE);

  for (int t2 = 0; t2 < NKT - 4; t2 += 2) {
    VM8; BAR;
    rd_a(SL(t2), offA0, 4, aHi);
    STAGE(t2 + 3);
    LG4; mfma16(aLo, bE, &acc[0]);
    VM8; BAR;
    rd_a(SL(t2 + 1), offA0, 0, aLo);
    rd_b(SL(t2 + 1), offB0, bO);
    LG8; mfma16(aHi, bE, &acc[4]);
    VM8; BAR;
    rd_a(SL(t2 + 1), offA0, 4, aHi);
    STAGE(t2 + 4);
    LG4; mfma16(aLo, bO, &acc[0]);
    VM8; BAR;
    rd_a(SL(t2 + 2), offA0, 0, aLo);
    rd_b(SL(t2 + 2), offB0, bE);
    LG8; mfma16(aHi, bO, &acc[4]);
  }

  VM8; BAR;
  rd_a(SL(NKT - 4), offA0, 4, aHi);
  STAGE(NKT - 1);
  LG4; mfma16(aLo, bE, &acc[0]);
  VM8; BAR;
  rd_a(SL(NKT - 3), offA0, 0, aLo);
  rd_b(SL(NKT - 3), offB0, bO);
  LG8; mfma16(aHi, bE, &acc[4]);
  VM8; BAR;
  rd_a(SL(NKT - 3), offA0, 4, aHi);
  LG4; mfma16(aLo, bO, &acc[0]);
  VM4; BAR;
  rd_a(SL(NKT - 2), offA0, 0, aLo);
  rd_b(SL(NKT - 2), offB0, bE);
  LG8; mfma16(aHi, bO, &acc[4]);

  VM4; BAR;
  rd_a(SL(NKT - 2), offA0, 4, aHi);
  LG4; mfma16(aLo, bE, &acc[0]);
  VM0; BAR;
  rd_a(SL(NKT - 1), offA0, 0, aLo);
  rd_b(SL(NKT - 1), offB0, bO);
  LG8; mfma16(aHi, bE, &acc[4]);
  BAR;
  rd_a(SL(NKT - 1), offA0, 4, aHi);
  LG4; mfma16(aLo, bO, &acc[0]);
  LG0; mfma16(aHi, bO, &acc[4]);
#undef STAGE
#undef SL
}

// ---------------------------------------------------------------------------
// 128^2 / 4-wave GEMM loop (unchanged from r13; used by pv).
// ---------------------------------------------------------------------------
__device__ __forceinline__ void gemm128(const _Float16* Ab, int lda,
                                        const _Float16* Bb, int ldb,
                                        int NKT, _Float16* lds,
                                        int w, int lane, int wr, int wc,
                                        int lr, int quad, v4f acc[4][4]) {
  const int offA0 = (wr + lr) * 32 + ((quad ^ (((wr + lr) >> 1) & 3)) * 8);
  const int offB0 = 4096 + (wc + lr) * 32 + ((quad ^ (((wc + lr) >> 1) & 3)) * 8);

  const int u0 = w * 128 + lane;
  const int u1 = u0 + 64;
  const int r0 = u0 >> 2, c0 = (u0 & 3) ^ ((r0 >> 1) & 3);
  const int r1 = u1 >> 2, c1 = (u1 & 3) ^ ((r1 >> 1) & 3);
  const _Float16* pA0 = Ab + (size_t)r0 * lda + c0 * 8;
  const _Float16* pA1 = Ab + (size_t)r1 * lda + c1 * 8;
  const _Float16* pB0 = Bb + (size_t)r0 * ldb + c0 * 8;
  const _Float16* pB1 = Bb + (size_t)r1 * ldb + c1 * 8;
  const int dA0 = (w * 128) * 8;
  const int dA1 = (w * 128 + 64) * 8;

#define STAGE(T)                                                             \
  do {                                                                       \
    _Float16* Ld = lds + ((T) & 3) * 8192;                                   \
    async16(pA0 + (T) * 32, Ld + dA0);                                       \
    async16(pA1 + (T) * 32, Ld + dA1);                                       \
    async16(pB0 + (T) * 32, Ld + 4096 + dA0);                                \
    async16(pB1 + (T) * 32, Ld + 4096 + dA1);                                \
  } while (0)

  STAGE(0);
  STAGE(1);
  STAGE(2);
  VM8;
  BAR;

  for (int t = 0; t < NKT; ++t) {
    const _Float16* U = lds + (t & 3) * 8192;
    v8h a[4], b[4];
    rd_a(U, offA0, 0, a);
    rd_b(U, offB0, b);
    if (t < NKT - 2) { VM4; } else { VM0; }
    BAR;
    SBAR;
    if (t + 3 < NKT) STAGE(t + 3);
    LG0;
    mfma16(a, b, &acc[0]);
  }
#undef STAGE
}

// Bijective XCD-aware swizzle (proj grid 768 % 8 == 0).
__device__ __forceinline__ void grid_swz(int& bx, int& by) {
  const int gx = gridDim.x;
  const int n = gx * gridDim.y;
  const int f = blockIdx.x + blockIdx.y * gx;
  const int s = (f & 7) * (n >> 3) + (f >> 3);
  bx = s % gx;
  by = s / gx;
}

// ---------------------------------------------------------------------------
// fp32 -> fp16, 8 elems/thread.
// ---------------------------------------------------------------------------
__global__ __launch_bounds__(256)
void cvt_f16(const float* __restrict__ src, _Float16* __restrict__ dst) {
  const int i = (blockIdx.x * 256 + threadIdx.x) * 8;
  float4 a = *(const float4*)(src + i);
  float4 b = *(const float4*)(src + i + 4);
  v8h o = {(_Float16)a.x, (_Float16)a.y, (_Float16)a.z, (_Float16)a.w,
           (_Float16)b.x, (_Float16)b.y, (_Float16)b.z, (_Float16)b.w};
  *(v8h*)(dst + i) = o;
}

__global__ __launch_bounds__(256)
void cvt_f16_w(const float* __restrict__ Wq, const float* __restrict__ Wk,
               const float* __restrict__ Wv, _Float16* __restrict__ dst) {
  const int bid = blockIdx.x;
  const int m = bid >> 9;
  const float* src = (m == 0) ? Wq : (m == 1) ? Wk : Wv;
  const int i = ((bid & 511) * 256 + threadIdx.x) * 8;
  float4 a = *(const float4*)(src + i);
  float4 b = *(const float4*)(src + i + 4);
  v8h o = {(_Float16)a.x, (_Float16)a.y, (_Float16)a.z, (_Float16)a.w,
           (_Float16)b.x, (_Float16)b.y, (_Float16)b.z, (_Float16)b.w};
  *(v8h*)(dst + (size_t)m * 1048576 + i) = o;
}

// ---------------------------------------------------------------------------
// Projection (r10 form, unchanged): C[m][n] = X[m][:].W[n][:], n packed Q|K|V.
// ---------------------------------------------------------------------------
__global__ __launch_bounds__(512, 2)
void proj_gemm(const _Float16* __restrict__ X, const _Float16* __restrict__ W,
               _Float16* __restrict__ Qb, _Float16* __restrict__ Kb,
               _Float16* __restrict__ Vt) {
  __shared__ _Float16 lds[65536];
  const int tid = threadIdx.x;
  int bx, by;
  grid_swz(bx, by);
  const int n0 = bx * BN, m0 = by * BM;
  const int which = n0 >> 10;
  const int nw = n0 & 1023;

  const int lane = tid & 63, w = tid >> 6;
  const int wr = (w >> 2) * 128, wc = (w & 3) * 64;
  const int lr = lane & 15, quad = lane >> 4;

  v4f acc[8][4];
#pragma unroll
  for (int i = 0; i < 8; ++i)
#pragma unroll
    for (int j = 0; j < 4; ++j) acc[i][j] = (v4f){0.f, 0.f, 0.f, 0.f};

  gemm_loop(X + (size_t)m0 * 1024, 1024, W + (size_t)n0 * 1024, 1024,
            32, lds, w, lane, wr, wc, lr, quad, acc);

#pragma unroll
  for (int i = 0; i < 8; ++i) {
    const int r0 = m0 + wr + i * 16 + quad * 4;
#pragma unroll
    for (int j = 0; j < 4; ++j) {
      const int cl = wc + j * 16 + lr;
      if (which < 2) {
        _Float16* dst = (which == 0) ? Qb : Kb;
        const int col = nw + cl;
#pragma unroll
        for (int rg = 0; rg < 4; ++rg)
          dst[(size_t)(r0 + rg) * 1024 + col] = (_Float16)acc[i][j][rg];
      } else {
        const int d = nw + cl;
        const int b = r0 >> 11, s = r0 & 2047;
        v4h o = {(_Float16)acc[i][j][0], (_Float16)acc[i][j][1],
                 (_Float16)acc[i][j][2], (_Float16)acc[i][j][3]};
        *(v4h*)(Vt + (size_t)b * 1024 * 2048 + (size_t)d * 2048 + s) = o;
      }
    }
  }
}

// ---------------------------------------------------------------------------
// Scores: 256x256 tiles, 256^2 8-wave core, triangular 288-block grid.
// f -> XCD chunk swizzle (36 tiles = one batch triangle per XCD) -> exact
// integer decode (by = max b: b(b+1)/2 <= t).  Diagonal tile masks cc>rr;
// strictly-upper tiles never launched (consumers read only causal prefixes).
// ---------------------------------------------------------------------------
__global__ __launch_bounds__(512, 2)
void scores_gemm(const _Float16* __restrict__ Q, const _Float16* __restrict__ K,
                 _Float16* __restrict__ Sc) {
  __shared__ _Float16 lds[65536];
  const int tid = threadIdx.x;
  const int f = blockIdx.x;                      // 0..287
  const int s = (f & 7) * 36 + (f >> 3);         // bijective, 288 = 8*36
  const int bz = s / 36;
  const int t1d = s % 36;                        // 0..35 lower-tri index

  int by = 0;
  while ((by + 1) * (by + 2) / 2 <= t1d) ++by;   // <= 7 iters, wave-uniform
  const int bx = t1d - by * (by + 1) / 2;        // 0..by

  const int m0 = by * 256, n0 = bx * 256;
  _Float16* Cb = Sc + (size_t)bz * 2048 * 2048;
  const _Float16* Qz = Q + (size_t)bz * 2048 * 1024;
  const _Float16* Kz = K + (size_t)bz * 2048 * 1024;

  const int lane = tid & 63, w = tid >> 6;
  const int wr = (w >> 2) * 128, wc = (w & 3) * 64;
  const int lr = lane & 15, quad = lane >> 4;

  v4f acc[8][4];
#pragma unroll
  for (int i = 0; i < 8; ++i)
#pragma unroll
    for (int j = 0; j < 4; ++j) acc[i][j] = (v4f){0.f, 0.f, 0.f, 0.f};

  gemm_loop(Qz + (size_t)m0 * 1024, 1024, Kz + (size_t)n0 * 1024, 1024,
            32, lds, w, lane, wr, wc, lr, quad, acc);

  const _Float16 ninf = (_Float16)(-__builtin_inff());
  const bool diag = (bx == by);
#pragma unroll
  for (int i = 0; i < 8; ++i) {
    const int r0 = m0 + wr + i * 16 + quad * 4;
#pragma unroll
    for (int j = 0; j < 4; ++j) {
      const int cc = n0 + wc + j * 16 + lr;
#pragma unroll
      for (int rg = 0; rg < 4; ++rg) {
        const int rr = r0 + rg;
        _Float16 v = (_Float16)acc[i][j][rg];
        Cb[(size_t)rr * 2048 + cc] = (diag && cc > rr) ? ninf : v;
      }
    }
  }
}

// ---------------------------------------------------------------------------
// Row softmax in place (f16); valid prefix [0, (q/128+1)*128).  (All read
// positions <= 256-aligned prefix are written: values or diag-tile -inf.)
// ---------------------------------------------------------------------------
__global__ __launch_bounds__(256)
void softmax_rows(_Float16* __restrict__ Sc) {
  _Float16* base = Sc + (size_t)blockIdx.x * 2048;
  const int q = blockIdx.x & 2047;
  const int ktile = ((q >> 7) + 1) << 7;
  const int tid = threadIdx.x;
  const int lane = tid & 63, w = tid >> 6;
  const bool active = tid * 8 < ktile;

  float f[8];
  if (active) {
    v8h pv = *(const v8h*)(base + tid * 8);
#pragma unroll
    for (int j = 0; j < 8; ++j) f[j] = (float)pv[j];
  } else {
#pragma unroll
    for (int j = 0; j < 8; ++j) f[j] = -__builtin_inff();
  }

  float mx = f[0];
#pragma unroll
  for (int j = 1; j < 8; ++j) mx = fmaxf(mx, f[j]);
#pragma unroll
  for (int off = 32; off; off >>= 1) mx = fmaxf(mx, __shfl_xor(mx, off));
  __shared__ float redm[4], reds[4];
  if (lane == 0) redm[w] = mx;
  __syncthreads();
  mx = fmaxf(fmaxf(redm[0], redm[1]), fmaxf(redm[2], redm[3]));

  const float scale = 0.03125f;                  // 1/sqrt(1024)
  float e[8], s = 0.f;
#pragma unroll
  for (int j = 0; j < 8; ++j) {
    e[j] = __expf((f[j] - mx) * scale);
    s += e[j];
  }
#pragma unroll
  for (int off = 32; off; off >>= 1) s += __shfl_xor(s, off);
  if (lane == 0) reds[w] = s;
  __syncthreads();
  s = reds[0] + reds[1] + reds[2] + reds[3];
  const float inv = 1.0f / s;
  if (active) {
    v8h pv;
#pragma unroll
    for (int j = 0; j < 8; ++j) pv[j] = (_Float16)(e[j] * inv);
    *(v8h*)(base + tid * 8) = pv;
  }
}

// ---------------------------------------------------------------------------
// Out (fp32): antithetic-paired PV (unchanged from r13).  Block (bx,p,bz)
// computes q-tile p then 15-p: exactly 68 K-tiles per block; 512 blocks.
// ---------------------------------------------------------------------------
__global__ __launch_bounds__(256, 2)
void pv_gemm(const _Float16* __restrict__ P, const _Float16* __restrict__ Vt,
             float* __restrict__ Out) {
  __shared__ _Float16 lds[32768];
  const int tid = threadIdx.x;
  const int bxx = blockIdx.x;                    // 0..7 (N-tile of 128)
  const int pair = blockIdx.y;                   // 0..7
  const int bz = blockIdx.z;
  const int n0 = bxx * 128;
  const _Float16* Pb = P + (size_t)bz * 2048 * 2048;
  const _Float16* Vb = Vt + (size_t)bz * 1024 * 2048;
  float* Cb = Out + (size_t)bz * 2048 * 1024;

  const int lane = tid & 63, w = tid >> 6;
  const int wr = (w >> 1) * 64, wc = (w & 1) * 64;
  const int lr = lane & 15, quad = lane >> 4;

#pragma unroll
  for (int part = 0; part < 2; ++part) {
    const int by = part ? (15 - pair) : pair;
    const int NKT = part ? ((16 - pair) * 4) : ((pair + 1) * 4);
    const int m0 = by * 128;

    v4f acc[4][4];
#pragma unroll
    for (int i = 0; i < 4; ++i)
#pragma unroll
      for (int j = 0; j < 4; ++j) acc[i][j] = (v4f){0.f, 0.f, 0.f, 0.f};

    gemm128(Pb + (size_t)m0 * 2048, 2048, Vb + (size_t)n0 * 2048, 2048,
            NKT, lds, w, lane, wr, wc, lr, quad, acc);

#pragma unroll
    for (int i = 0; i < 4; ++i) {
      const int r0 = m0 + wr + i * 16 + quad * 4;
#pragma unroll
      for (int j = 0; j < 4; ++j) {
        const int cc = n0 + wc + j * 16 + lr;
#pragma unroll
        for (int rg = 0; rg < 4; ++rg)
          Cb[(size_t)(r0 + rg) * 1024 + cc] = acc[i][j][rg];
      }
    }
    __syncthreads();
  }
}

// ---------------------------------------------------------------------------
extern "C" void kernel_launch(void* const* d_in, const int* in_sizes, int n_in,
                              void* d_out, int out_size, void* d_ws, size_t ws_size,
                              hipStream_t stream) {
  const int B = 8, S = 2048, D = 1024;
  const int M = B * S;                           // 16384
  const float* x  = (const float*)d_in[0];
  const float* Wq = (const float*)d_in[1];
  const float* Wk = (const float*)d_in[2];
  const float* Wv = (const float*)d_in[3];
  float* out = (float*)d_out;

  char* ws = (char*)d_ws;
  _Float16* Qb = (_Float16*)ws;                          // [M][1024]
  _Float16* Kb = (_Float16*)(ws + (size_t)33554432);     // [M][1024]
  _Float16* Vt = (_Float16*)(ws + (size_t)67108864);     // [B][1024][2048]
  _Float16* Sc = (_Float16*)(ws + (size_t)100663296);    // [B][2048][2048]
  _Float16* xh = Sc;                                     // alias (dead later)
  _Float16* Wh = Sc + (size_t)M * D;                     // alias

  // 1) fp32 -> fp16 converts
  cvt_f16<<<(M * D) / 2048, 256, 0, stream>>>(x, xh);
  cvt_f16_w<<<1536, 256, 0, stream>>>(Wq, Wk, Wv, Wh);

  // 2) QKV projection (r10 256^2 GEMM)
  proj_gemm<<<dim3(12, M / BM, 1), 512, 0, stream>>>(xh, Wh, Qb, Kb, Vt);

  // 3) raw scores: 256^2 core, triangular 288-block grid
  scores_gemm<<<288, 512, 0, stream>>>(Qb, Kb, Sc);

  // 4) softmax on 128-aligned valid prefix
  softmax_rows<<<B * S, 256, 0, stream>>>(Sc);

  // 5) out = P @ Vt, antithetic-paired balanced grid (512 blocks, 2/CU)
  pv_gemm<<<dim3(8, 8, B), 256, 0, stream>>>(Sc, Vt, out);
}